// Round 2
// baseline (815.001 us; speedup 1.0000x reference)
//
#include <hip/hip_runtime.h>

// Problem constants: B=8, S=384, D=1024, H=16, hd=64
#define S_ 384
#define D_ 1024
#define H_ 16
#define HD_ 64

typedef short bf16x8 __attribute__((ext_vector_type(8)));
typedef float f32x4 __attribute__((ext_vector_type(4)));

__device__ __forceinline__ unsigned short f32_to_bf16(float f) {
  unsigned u = __float_as_uint(f);
  u += 0x7FFFu + ((u >> 16) & 1u);   // round-to-nearest-even
  return (unsigned short)(u >> 16);
}
__device__ __forceinline__ float bf16_to_f32(unsigned short h) {
  return __uint_as_float(((unsigned)h) << 16);
}

// ---------------- cast f32 -> bf16 (element-wise, float4 vectorized) --------
__global__ void cast_kernel(const float* __restrict__ src,
                            unsigned short* __restrict__ dst, int n4) {
  int i = blockIdx.x * blockDim.x + threadIdx.x;
  if (i >= n4) return;
  float4 v = ((const float4*)src)[i];
  ushort4 o;
  o.x = f32_to_bf16(v.x); o.y = f32_to_bf16(v.y);
  o.z = f32_to_bf16(v.z); o.w = f32_to_bf16(v.w);
  ((ushort4*)dst)[i] = o;
}

// ---------------- transpose + cast: W[K][N] f32 -> Wt[N][K] bf16 ------------
__global__ void transpose_cast_kernel(const float* __restrict__ W,
                                      unsigned short* __restrict__ Wt,
                                      int K, int N) {
  __shared__ float tile[32][33];
  int n0 = blockIdx.x * 32, k0 = blockIdx.y * 32;
  int tx = threadIdx.x, ty = threadIdx.y;  // (32, 8)
#pragma unroll
  for (int yy = 0; yy < 32; yy += 8)
    tile[ty + yy][tx] = W[(size_t)(k0 + ty + yy) * N + n0 + tx];
  __syncthreads();
#pragma unroll
  for (int yy = 0; yy < 32; yy += 8)
    Wt[(size_t)(n0 + ty + yy) * K + k0 + tx] = f32_to_bf16(tile[tx][ty + yy]);
}

// ---------------- bf16 MFMA GEMM: C[M][N] = A[M][1024] * Bt[N][1024]^T ------
// 128x128 tile, 4 waves (2x2 of 64x64), BK=32, reg-staged LDS.
// MODE 0: QKV epilogue (scatter to Qb/Kb/Vb bf16, +qkv_b)
// MODE 1: out-proj epilogue (f32 to Cout, +out_b)
template <int MODE>
__global__ __launch_bounds__(256) void gemm_bt_kernel(
    const unsigned short* __restrict__ A, const unsigned short* __restrict__ Bt,
    const float* __restrict__ bias, unsigned short* __restrict__ Qb,
    unsigned short* __restrict__ Kb, unsigned short* __restrict__ Vb,
    float* __restrict__ Cout) {
  const int K = 1024;
  __shared__ __align__(16) unsigned short As[128 * 32];
  __shared__ __align__(16) unsigned short Bs[128 * 32];
  const int tid = threadIdx.x;
  const int m0 = blockIdx.x * 128, n0 = blockIdx.y * 128;
  const int wid = tid >> 6, lane = tid & 63;
  const int wr = wid >> 1, wc = wid & 1;
  const int l15 = lane & 15, lg = lane >> 4;

  f32x4 acc[4][4];
#pragma unroll
  for (int m = 0; m < 4; ++m)
#pragma unroll
    for (int n = 0; n < 4; ++n) acc[m][n] = (f32x4){0.f, 0.f, 0.f, 0.f};

  for (int k0 = 0; k0 < K; k0 += 32) {
    __syncthreads();
#pragma unroll
    for (int p = 0; p < 2; ++p) {
      int tt = p * 256 + tid;
      int row = tt >> 2, kk = (tt & 3) * 8;
      *(int4*)&As[row * 32 + kk] =
          *(const int4*)&A[(size_t)(m0 + row) * K + k0 + kk];
      *(int4*)&Bs[row * 32 + kk] =
          *(const int4*)&Bt[(size_t)(n0 + row) * K + k0 + kk];
    }
    __syncthreads();
    bf16x8 af[4], bf[4];
#pragma unroll
    for (int m = 0; m < 4; ++m)
      af[m] = *(bf16x8*)&As[(wr * 64 + m * 16 + l15) * 32 + lg * 8];
#pragma unroll
    for (int n = 0; n < 4; ++n)
      bf[n] = *(bf16x8*)&Bs[(wc * 64 + n * 16 + l15) * 32 + lg * 8];
#pragma unroll
    for (int m = 0; m < 4; ++m)
#pragma unroll
      for (int n = 0; n < 4; ++n)
        acc[m][n] =
            __builtin_amdgcn_mfma_f32_16x16x32_bf16(af[m], bf[n], acc[m][n], 0, 0, 0);
  }

  // epilogue: C/D layout col = lane&15, row = (lane>>4)*4 + reg  [m89-verified]
#pragma unroll
  for (int m = 0; m < 4; ++m) {
#pragma unroll
    for (int n = 0; n < 4; ++n) {
#pragma unroll
      for (int r = 0; r < 4; ++r) {
        int R = m0 + wr * 64 + m * 16 + lg * 4 + r;
        int c = n0 + wc * 64 + n * 16 + l15;
        float val = acc[m][n][r] + bias[c];
        if (MODE == 0) {
          int b = R / S_, s = R % S_;
          int hh = c / 192, rr = c % 192;
          int sel = rr >> 6, dd = rr & 63;
          size_t addr = ((size_t)(b * H_ + hh) * S_ + s) * HD_ + dd;
          unsigned short bv = f32_to_bf16(val);
          if (sel == 0) Qb[addr] = bv;
          else if (sel == 1) Kb[addr] = bv;
          else Vb[addr] = bv;
        } else {
          Cout[(size_t)R * D_ + c] = val;
        }
      }
    }
  }
}

// ---------------- fused attention: logits(+XL bias) -> softmax -> PV --------
// grid: (128 = b*h, 24 = S/16). block 256. f32 compute.
__global__ __launch_bounds__(256) void attn_kernel(
    const unsigned short* __restrict__ Qb, const unsigned short* __restrict__ Kb,
    const unsigned short* __restrict__ Vb, const unsigned short* __restrict__ Tb,
    float* __restrict__ attn_out, unsigned short* __restrict__ Vals) {
  __shared__ float qs[16][64];
  __shared__ float ks[64][65];   // +1 pad: kill bank conflicts on stride-64 reads
  __shared__ float lg[16][385];
  const int tid = threadIdx.x;
  const int bh = blockIdx.x;    // b*16 + h
  const int itile = blockIdx.y; // 0..23
  const int hh = bh & 15;
  const int i0 = itile << 4;
  const size_t base = (size_t)bh * (S_ * HD_);

  {  // Q tile: 16x64
    int e = tid << 2;
    int row = e >> 6, col = e & 63;
    ushort4 v = *(const ushort4*)&Qb[base + (size_t)(i0 + row) * HD_ + col];
    qs[row][col + 0] = bf16_to_f32(v.x);
    qs[row][col + 1] = bf16_to_f32(v.y);
    qs[row][col + 2] = bf16_to_f32(v.z);
    qs[row][col + 3] = bf16_to_f32(v.w);
  }

  const int jl = tid & 63;
  const int ig = tid >> 6;
  // rpem flat-reshape mapping:
  //   T row = (i&15)*24 + (j>>4) - 24*h - (i>>4) + 384,  col = (j&15)*64 + dd
  const int tconst = 384 - hh * 24 - itile;

  for (int jt = 0; jt < 6; ++jt) {
    const int j0 = jt << 6;
    __syncthreads();
#pragma unroll
    for (int pp = 0; pp < 4; ++pp) {  // K tile 64x64
      int e = (pp << 10) + (tid << 2);
      int row = e >> 6, col = e & 63;
      ushort4 v = *(const ushort4*)&Kb[base + (size_t)(j0 + row) * HD_ + col];
      ks[row][col + 0] = bf16_to_f32(v.x);
      ks[row][col + 1] = bf16_to_f32(v.y);
      ks[row][col + 2] = bf16_to_f32(v.z);
      ks[row][col + 3] = bf16_to_f32(v.w);
    }
    __syncthreads();
    const int j = j0 + jl;
    const int j2h = j >> 4;
    const uint4* tseg = (const uint4*)(Tb + ((size_t)(j & 15) << 6));
#pragma unroll
    for (int r = 0; r < 4; ++r) {
      const int il = ig + (r << 2);
      const int trow = il * 24 + j2h + tconst;
      const uint4* tpr = tseg + (size_t)trow * 128;  // 128 uint4 per 1024-col row
      float a1 = 0.f, a2 = 0.f;
#pragma unroll
      for (int d8 = 0; d8 < 8; ++d8) {
        uint4 tv = tpr[d8];
        const int d = d8 << 3;
        unsigned wv[4] = {tv.x, tv.y, tv.z, tv.w};
#pragma unroll
        for (int q2 = 0; q2 < 4; ++q2) {
          float tl = __uint_as_float(wv[q2] << 16);
          float th = __uint_as_float(wv[q2] & 0xFFFF0000u);
          float q0v = qs[il][d + q2 * 2 + 0];
          float q1v = qs[il][d + q2 * 2 + 1];
          a1 += q0v * ks[jl][d + q2 * 2 + 0] + q1v * ks[jl][d + q2 * 2 + 1];
          a2 += q0v * tl + q1v * th;
        }
      }
      lg[il][j] = a1 * 0.125f + a2;
    }
  }
  __syncthreads();

  {  // softmax: 16 lanes per row
    const int row = tid >> 4, l16 = tid & 15;
    float m = -1e30f;
    for (int j = l16; j < S_; j += 16) m = fmaxf(m, lg[row][j]);
#pragma unroll
    for (int o = 8; o; o >>= 1) m = fmaxf(m, __shfl_xor(m, o, 16));
    float s = 0.f;
    for (int j = l16; j < S_; j += 16) {
      float e = __expf(lg[row][j] - m);
      lg[row][j] = e;
      s += e;
    }
#pragma unroll
    for (int o = 8; o; o >>= 1) s += __shfl_xor(s, o, 16);
    const float inv = 1.0f / s;
    float* ao = attn_out + (size_t)bh * (S_ * S_) + (size_t)(i0 + row) * S_;
    for (int j = l16; j < S_; j += 16) {
      float p = lg[row][j] * inv;
      lg[row][j] = p;
      ao[j] = p;
    }
  }
  __syncthreads();

  {  // PV: values[i][dd] = sum_j p[i][j] * V[j][dd]
    float a0 = 0.f, a1 = 0.f, a2 = 0.f, a3 = 0.f;
    const unsigned short* vp = Vb + base + jl;
    const int r0 = ig << 2;
#pragma unroll 8
    for (int j = 0; j < S_; ++j) {
      float v = bf16_to_f32(vp[(size_t)j * HD_]);
      a0 += lg[r0 + 0][j] * v;
      a1 += lg[r0 + 1][j] * v;
      a2 += lg[r0 + 2][j] * v;
      a3 += lg[r0 + 3][j] * v;
    }
    const int b = bh >> 4;
    unsigned short* o =
        Vals + ((size_t)(b * S_ + i0 + r0)) * D_ + hh * HD_ + jl;
    o[0 * D_] = f32_to_bf16(a0);
    o[1 * D_] = f32_to_bf16(a1);
    o[2 * D_] = f32_to_bf16(a2);
    o[3 * D_] = f32_to_bf16(a3);
  }
}

// ---------------------------------------------------------------------------
extern "C" void kernel_launch(void* const* d_in, const int* in_sizes, int n_in,
                              void* d_out, int out_size, void* d_ws,
                              size_t ws_size, hipStream_t stream) {
  (void)in_sizes; (void)n_in; (void)out_size; (void)ws_size;
  const float* x     = (const float*)d_in[0];  // (8,384,1024)
  const float* qkv_w = (const float*)d_in[1];  // (1024,3072)
  const float* qkv_b = (const float*)d_in[2];  // (3072,)
  const float* out_w = (const float*)d_in[3];  // (1024,1024)
  const float* out_b = (const float*)d_in[4];  // (1024,)
  const float* rpe   = (const float*)d_in[5];  // (1023,1024)

  float* out  = (float*)d_out;        // 3145728 f32
  float* attn = out + 3145728;        // 18874368 f32

  unsigned short* ws  = (unsigned short*)d_ws;
  unsigned short* xb  = ws;                 // 3072*1024
  unsigned short* Wt  = xb + 3145728;       // 3072*1024 (qkv_w^T)
  unsigned short* Wot = Wt + 3145728;       // 1024*1024 (out_w^T)
  unsigned short* Tb  = Wot + 1048576;      // 1023*1024
  unsigned short* Qb  = Tb + 1047552;       // (b,h,s,hd)
  unsigned short* Kb  = Qb + 3145728;
  unsigned short* Vb  = Kb + 3145728;
  unsigned short* Vals = Vb + 3145728;      // (b*s, 1024) bf16

  // 1) casts / transposes
  cast_kernel<<<3072, 256, 0, stream>>>(x, xb, 786432);
  cast_kernel<<<1023, 256, 0, stream>>>(rpe, Tb, 261888);
  transpose_cast_kernel<<<dim3(96, 32), dim3(32, 8), 0, stream>>>(qkv_w, Wt, 1024, 3072);
  transpose_cast_kernel<<<dim3(32, 32), dim3(32, 8), 0, stream>>>(out_w, Wot, 1024, 1024);

  // 2) QKV projection (M=3072, N=3072)
  gemm_bt_kernel<0><<<dim3(24, 24), 256, 0, stream>>>(xb, Wt, qkv_b, Qb, Kb, Vb, nullptr);

  // 3) fused attention (+XL relative bias), writes attention probs + values
  attn_kernel<<<dim3(128, 24), 256, 0, stream>>>(Qb, Kb, Vb, Tb, attn, Vals);

  // 4) output projection (M=3072, N=1024)
  gemm_bt_kernel<1><<<dim3(24, 8), 256, 0, stream>>>(Vals, Wot, out_b, nullptr, nullptr, nullptr, out);
}

// Round 3
// 294.208 us; speedup vs baseline: 2.7702x; 2.7702x over previous
//
#include <hip/hip_runtime.h>

// Problem constants: B=8, S=384, D=1024, H=16, hd=64
#define S_ 384
#define D_ 1024
#define H_ 16
#define HD_ 64

typedef short bf16x8 __attribute__((ext_vector_type(8)));
typedef float f32x4 __attribute__((ext_vector_type(4)));

__device__ __forceinline__ unsigned short f32_to_bf16(float f) {
  unsigned u = __float_as_uint(f);
  u += 0x7FFFu + ((u >> 16) & 1u);   // round-to-nearest-even
  return (unsigned short)(u >> 16);
}
__device__ __forceinline__ float bf16_to_f32(unsigned short h) {
  return __uint_as_float(((unsigned)h) << 16);
}

// ---------------- cast f32 -> bf16 (element-wise, float4 vectorized) --------
__global__ void cast_kernel(const float* __restrict__ src,
                            unsigned short* __restrict__ dst, int n4) {
  int i = blockIdx.x * blockDim.x + threadIdx.x;
  if (i >= n4) return;
  float4 v = ((const float4*)src)[i];
  ushort4 o;
  o.x = f32_to_bf16(v.x); o.y = f32_to_bf16(v.y);
  o.z = f32_to_bf16(v.z); o.w = f32_to_bf16(v.w);
  ((ushort4*)dst)[i] = o;
}

// ---------------- transpose + cast: W[K][N] f32 -> Wt[N][K] bf16 ------------
__global__ void transpose_cast_kernel(const float* __restrict__ W,
                                      unsigned short* __restrict__ Wt,
                                      int K, int N) {
  __shared__ float tile[32][33];
  int n0 = blockIdx.x * 32, k0 = blockIdx.y * 32;
  int tx = threadIdx.x, ty = threadIdx.y;  // (32, 8)
#pragma unroll
  for (int yy = 0; yy < 32; yy += 8)
    tile[ty + yy][tx] = W[(size_t)(k0 + ty + yy) * N + n0 + tx];
  __syncthreads();
#pragma unroll
  for (int yy = 0; yy < 32; yy += 8)
    Wt[(size_t)(n0 + ty + yy) * K + k0 + tx] = f32_to_bf16(tile[tx][ty + yy]);
}

// ---------------- bf16 MFMA GEMM: C[M][N] = A[M][1024] * Bt[N][1024]^T ------
// 128x128 tile, 4 waves (2x2 of 64x64), BK=32, reg-staged LDS.
// MODE 0: QKV epilogue (scatter to Qb/Kb bf16, V transposed to Vt, +qkv_b)
// MODE 1: out-proj epilogue (f32 to Cout, +out_b)
template <int MODE>
__global__ __launch_bounds__(256) void gemm_bt_kernel(
    const unsigned short* __restrict__ A, const unsigned short* __restrict__ Bt,
    const float* __restrict__ bias, unsigned short* __restrict__ Qb,
    unsigned short* __restrict__ Kb, unsigned short* __restrict__ Vt,
    float* __restrict__ Cout) {
  const int K = 1024;
  __shared__ __align__(16) unsigned short As[128 * 32];
  __shared__ __align__(16) unsigned short Bs[128 * 32];
  const int tid = threadIdx.x;
  const int m0 = blockIdx.x * 128, n0 = blockIdx.y * 128;
  const int wid = tid >> 6, lane = tid & 63;
  const int wr = wid >> 1, wc = wid & 1;
  const int l15 = lane & 15, lg = lane >> 4;

  f32x4 acc[4][4];
#pragma unroll
  for (int m = 0; m < 4; ++m)
#pragma unroll
    for (int n = 0; n < 4; ++n) acc[m][n] = (f32x4){0.f, 0.f, 0.f, 0.f};

  for (int k0 = 0; k0 < K; k0 += 32) {
    __syncthreads();
#pragma unroll
    for (int p = 0; p < 2; ++p) {
      int tt = p * 256 + tid;
      int row = tt >> 2, kk = (tt & 3) * 8;
      *(int4*)&As[row * 32 + kk] =
          *(const int4*)&A[(size_t)(m0 + row) * K + k0 + kk];
      *(int4*)&Bs[row * 32 + kk] =
          *(const int4*)&Bt[(size_t)(n0 + row) * K + k0 + kk];
    }
    __syncthreads();
    bf16x8 af[4], bf[4];
#pragma unroll
    for (int m = 0; m < 4; ++m)
      af[m] = *(bf16x8*)&As[(wr * 64 + m * 16 + l15) * 32 + lg * 8];
#pragma unroll
    for (int n = 0; n < 4; ++n)
      bf[n] = *(bf16x8*)&Bs[(wc * 64 + n * 16 + l15) * 32 + lg * 8];
#pragma unroll
    for (int m = 0; m < 4; ++m)
#pragma unroll
      for (int n = 0; n < 4; ++n)
        acc[m][n] =
            __builtin_amdgcn_mfma_f32_16x16x32_bf16(af[m], bf[n], acc[m][n], 0, 0, 0);
  }

  // epilogue: C/D layout col = lane&15, row = (lane>>4)*4 + reg  [HW-verified]
#pragma unroll
  for (int m = 0; m < 4; ++m) {
#pragma unroll
    for (int n = 0; n < 4; ++n) {
#pragma unroll
      for (int r = 0; r < 4; ++r) {
        int R = m0 + wr * 64 + m * 16 + lg * 4 + r;
        int c = n0 + wc * 64 + n * 16 + l15;
        float val = acc[m][n][r] + bias[c];
        if (MODE == 0) {
          int b = R / S_, s = R % S_;
          int hh = c / 192, rr = c % 192;
          int sel = rr >> 6, dd = rr & 63;
          unsigned short bv = f32_to_bf16(val);
          if (sel == 0) {
            Qb[((size_t)(b * H_ + hh) * S_ + s) * HD_ + dd] = bv;
          } else if (sel == 1) {
            Kb[((size_t)(b * H_ + hh) * S_ + s) * HD_ + dd] = bv;
          } else {
            // V stored transposed: Vt[b,h,dd,s]
            Vt[((size_t)(b * H_ + hh) * HD_ + dd) * S_ + s] = bv;
          }
        } else {
          Cout[(size_t)R * D_ + c] = val;
        }
      }
    }
  }
}

// ---------------- XL-bias via MFMA, b-shared (2x waste) ---------------------
// grid (h=16, itile=24), 512 threads (8 waves). Wave w handles il = 2w, 2w+1.
// For fixed (il, jH): table row r = il*24 + jH + (384 - 24h - itile) is shared
// by all 8 batches -> MFMA A-rows = b. Writes bias f32 into the attention
// region of d_out at its final slot (attn2 reads then overwrites with probs).
__global__ __launch_bounds__(512) void bias_kernel(
    const unsigned short* __restrict__ Qb, const unsigned short* __restrict__ Tb,
    float* __restrict__ biasout) {
  const int hh = blockIdx.x;     // 0..15
  const int itile = blockIdx.y;  // 0..23
  const int tid = threadIdx.x;
  const int wid = tid >> 6, lane = tid & 63;
  const int l15 = lane & 15, lg = lane >> 4;
  const int C = 384 - 24 * hh - itile;
  const int i0 = itile * 16;

#pragma unroll
  for (int t = 0; t < 2; ++t) {
    const int il = wid * 2 + t;
    const int i = i0 + il;
    // A-frag: row = b (lanes 8..15 duplicate b&7), k = d
    const int b8 = l15 & 7;
    const size_t qaddr = ((size_t)(b8 * H_ + hh) * S_ + i) * HD_ + lg * 8;
    bf16x8 a0 = *(const bf16x8*)&Qb[qaddr];        // d in [0,32)
    bf16x8 a1 = *(const bf16x8*)&Qb[qaddr + 32];   // d in [32,64)
    const int rbase = il * 24 + C;
#pragma unroll 4
    for (int jH = 0; jH < 24; ++jH) {
      const unsigned short* trow = Tb + (size_t)(rbase + jH) * D_;
      // B-frag: col = jL (l15), k = d : T[r, jL*64 + d]
      bf16x8 b0 = *(const bf16x8*)&trow[l15 * 64 + lg * 8];
      bf16x8 b1 = *(const bf16x8*)&trow[l15 * 64 + 32 + lg * 8];
      f32x4 d = {0.f, 0.f, 0.f, 0.f};
      d = __builtin_amdgcn_mfma_f32_16x16x32_bf16(a0, b0, d, 0, 0, 0);
      d = __builtin_amdgcn_mfma_f32_16x16x32_bf16(a1, b1, d, 0, 0, 0);
      if (lg < 2) {  // D rows = b = lg*4+rr, valid b<8; cols = jL = l15
#pragma unroll
        for (int rr = 0; rr < 4; ++rr) {
          const int b = lg * 4 + rr;
          biasout[((size_t)(b * H_ + hh) * S_ + i) * S_ + jH * 16 + l15] = d[rr];
        }
      }
    }
  }
}

// ---------------- fused QK^T(+bias) -> softmax -> PV, all MFMA --------------
// grid (b*h=128, itile=24), 256 threads (4 waves).
__global__ __launch_bounds__(256) void attn2_kernel(
    const unsigned short* __restrict__ Qb, const unsigned short* __restrict__ Kb,
    const unsigned short* __restrict__ Vt, float* __restrict__ attn_out,
    unsigned short* __restrict__ Vals) {
  __shared__ float lgs[16][392];          // logits f32 (+8 pad)
  __shared__ unsigned short pb[16][392];  // probs bf16 (+8 pad)
  const int bh = blockIdx.x;
  const int itile = blockIdx.y;
  const int i0 = itile * 16;
  const size_t base = (size_t)bh * (S_ * HD_);
  const int tid = threadIdx.x, wid = tid >> 6, lane = tid & 63;
  const int l15 = lane & 15, lg = lane >> 4;

  // Q A-frags: row = il (l15), k = d
  const size_t qaddr = base + (size_t)(i0 + l15) * HD_ + lg * 8;
  bf16x8 qa0 = *(const bf16x8*)&Qb[qaddr];
  bf16x8 qa1 = *(const bf16x8*)&Qb[qaddr + 32];

  // ---- QK^T + bias: wave handles jH = wid*6 .. wid*6+5
#pragma unroll
  for (int t = 0; t < 6; ++t) {
    const int jH = wid * 6 + t;
    const int j0 = jH * 16;
    const size_t kaddr = base + (size_t)(j0 + l15) * HD_ + lg * 8;
    bf16x8 kb0 = *(const bf16x8*)&Kb[kaddr];
    bf16x8 kb1 = *(const bf16x8*)&Kb[kaddr + 32];
    f32x4 d = {0.f, 0.f, 0.f, 0.f};
    d = __builtin_amdgcn_mfma_f32_16x16x32_bf16(qa0, kb0, d, 0, 0, 0);
    d = __builtin_amdgcn_mfma_f32_16x16x32_bf16(qa1, kb1, d, 0, 0, 0);
#pragma unroll
    for (int rr = 0; rr < 4; ++rr) {  // D: row = il = lg*4+rr, col = jL = l15
      const int il = lg * 4 + rr;
      float bv = attn_out[((size_t)bh * S_ + i0 + il) * S_ + j0 + l15];
      lgs[il][j0 + l15] = d[rr] * 0.125f + bv;
    }
  }
  __syncthreads();

  // ---- softmax (16 lanes per row) + write probs f32 to out, bf16 to LDS
  {
    const int row = tid >> 4, l16 = tid & 15;
    float m = -1e30f;
    for (int j = l16; j < S_; j += 16) m = fmaxf(m, lgs[row][j]);
#pragma unroll
    for (int o = 8; o; o >>= 1) m = fmaxf(m, __shfl_xor(m, o, 16));
    float s = 0.f;
    for (int j = l16; j < S_; j += 16) {
      float e = __expf(lgs[row][j] - m);
      lgs[row][j] = e;
      s += e;
    }
#pragma unroll
    for (int o = 8; o; o >>= 1) s += __shfl_xor(s, o, 16);
    const float inv = 1.0f / s;
    float* ao = attn_out + ((size_t)bh * S_ + i0 + row) * S_;
    for (int j = l16; j < S_; j += 16) {
      float p = lgs[row][j] * inv;
      ao[j] = p;
      pb[row][j] = f32_to_bf16(p);
    }
  }
  __syncthreads();

  // ---- PV: wave wid owns d-tile d0 = wid*16. A = probs(16x384), B = Vt slice
  {
    const int d0 = wid * 16;
    f32x4 acc = {0.f, 0.f, 0.f, 0.f};
#pragma unroll 4
    for (int kc = 0; kc < 12; ++kc) {
      bf16x8 pa = *(const bf16x8*)&pb[l15][kc * 32 + lg * 8];
      bf16x8 vb = *(const bf16x8*)&Vt[base + (size_t)(d0 + l15) * S_ + kc * 32 + lg * 8];
      acc = __builtin_amdgcn_mfma_f32_16x16x32_bf16(pa, vb, acc, 0, 0, 0);
    }
    const int b = bh >> 4, hh = bh & 15;
#pragma unroll
    for (int rr = 0; rr < 4; ++rr) {
      const int il = lg * 4 + rr;
      Vals[((size_t)(b * S_ + i0 + il)) * D_ + hh * HD_ + d0 + l15] =
          f32_to_bf16(acc[rr]);
    }
  }
}

// ---------------------------------------------------------------------------
extern "C" void kernel_launch(void* const* d_in, const int* in_sizes, int n_in,
                              void* d_out, int out_size, void* d_ws,
                              size_t ws_size, hipStream_t stream) {
  (void)in_sizes; (void)n_in; (void)out_size; (void)ws_size;
  const float* x     = (const float*)d_in[0];  // (8,384,1024)
  const float* qkv_w = (const float*)d_in[1];  // (1024,3072)
  const float* qkv_b = (const float*)d_in[2];  // (3072,)
  const float* out_w = (const float*)d_in[3];  // (1024,1024)
  const float* out_b = (const float*)d_in[4];  // (1024,)
  const float* rpe   = (const float*)d_in[5];  // (1023,1024)

  float* out  = (float*)d_out;        // 3145728 f32
  float* attn = out + 3145728;        // 18874368 f32 (used as bias scratch first)

  unsigned short* ws  = (unsigned short*)d_ws;
  unsigned short* xb  = ws;                 // 3072*1024
  unsigned short* Wt  = xb + 3145728;       // 3072*1024 (qkv_w^T)
  unsigned short* Wot = Wt + 3145728;       // 1024*1024 (out_w^T)
  unsigned short* Tb  = Wot + 1048576;      // 1023*1024
  unsigned short* Qb  = Tb + 1047552;       // (b,h,s,hd)
  unsigned short* Kb  = Qb + 3145728;       // (b,h,s,hd)
  unsigned short* Vt  = Kb + 3145728;       // (b,h,hd,s)  transposed V
  unsigned short* Vals = Vt + 3145728;      // (b*s, 1024) bf16

  // 1) casts / transposes
  cast_kernel<<<3072, 256, 0, stream>>>(x, xb, 786432);
  cast_kernel<<<1023, 256, 0, stream>>>(rpe, Tb, 261888);
  transpose_cast_kernel<<<dim3(96, 32), dim3(32, 8), 0, stream>>>(qkv_w, Wt, 1024, 3072);
  transpose_cast_kernel<<<dim3(32, 32), dim3(32, 8), 0, stream>>>(out_w, Wot, 1024, 1024);

  // 2) QKV projection (M=3072, N=3072); V written transposed
  gemm_bt_kernel<0><<<dim3(24, 24), 256, 0, stream>>>(xb, Wt, qkv_b, Qb, Kb, Vt, nullptr);

  // 3) XL relative bias (MFMA, b-shared) -> staged f32 in attn-out slots
  bias_kernel<<<dim3(16, 24), 512, 0, stream>>>(Qb, Tb, attn);

  // 4) fused QK^T(+bias) -> softmax -> PV (all MFMA)
  attn2_kernel<<<dim3(128, 24), 256, 0, stream>>>(Qb, Kb, Vt, attn, Vals);

  // 5) output projection (M=3072, N=1024)
  gemm_bt_kernel<1><<<dim3(24, 8), 256, 0, stream>>>(Vals, Wot, out_b, nullptr, nullptr, nullptr, out);
}

// Round 4
// 272.589 us; speedup vs baseline: 2.9899x; 1.0793x over previous
//
#include <hip/hip_runtime.h>

// Problem constants: B=8, S=384, D=1024, H=16, hd=64
#define S_ 384
#define D_ 1024
#define H_ 16
#define HD_ 64

typedef short bf16x8 __attribute__((ext_vector_type(8)));
typedef float f32x4 __attribute__((ext_vector_type(4)));

#define LDS_AS3(p) ((__attribute__((address_space(3))) unsigned int*)(p))
#define GLB_AS1(p) ((const __attribute__((address_space(1))) unsigned int*)(p))

__device__ __forceinline__ unsigned short f32_to_bf16(float f) {
  unsigned u = __float_as_uint(f);
  u += 0x7FFFu + ((u >> 16) & 1u);   // round-to-nearest-even
  return (unsigned short)(u >> 16);
}
__device__ __forceinline__ float bf16_to_f32(unsigned short h) {
  return __uint_as_float(((unsigned)h) << 16);
}

// ---------------- cast f32 -> bf16 (element-wise, float4 vectorized) --------
__global__ void cast_kernel(const float* __restrict__ src,
                            unsigned short* __restrict__ dst, int n4) {
  int i = blockIdx.x * blockDim.x + threadIdx.x;
  if (i >= n4) return;
  float4 v = ((const float4*)src)[i];
  ushort4 o;
  o.x = f32_to_bf16(v.x); o.y = f32_to_bf16(v.y);
  o.z = f32_to_bf16(v.z); o.w = f32_to_bf16(v.w);
  ((ushort4*)dst)[i] = o;
}

// ---------------- transpose + cast: W[K][N] f32 -> Wt[N][K] bf16 ------------
__global__ void transpose_cast_kernel(const float* __restrict__ W,
                                      unsigned short* __restrict__ Wt,
                                      int K, int N) {
  __shared__ float tile[32][33];
  int n0 = blockIdx.x * 32, k0 = blockIdx.y * 32;
  int tx = threadIdx.x, ty = threadIdx.y;  // (32, 8)
#pragma unroll
  for (int yy = 0; yy < 32; yy += 8)
    tile[ty + yy][tx] = W[(size_t)(k0 + ty + yy) * N + n0 + tx];
  __syncthreads();
#pragma unroll
  for (int yy = 0; yy < 32; yy += 8)
    Wt[(size_t)(n0 + ty + yy) * K + k0 + tx] = f32_to_bf16(tile[tx][ty + yy]);
}

// ---------------- bf16 MFMA GEMM: C[M][N] = A[M][1024] * Bt[N][1024]^T ------
// 128x128 tile, 4 waves (2x2 of 64x64), BK=32, global_load_lds staging (m97).
// LDS slot byte = tt*16 (linear in thread order) == wave base + lane*16.
// MODE 0: QKV epilogue (scatter to Qb/Kb bf16, V transposed to Vt, +qkv_b)
// MODE 1: out-proj epilogue (f32 to Cout, +out_b)
template <int MODE>
__global__ __launch_bounds__(256) void gemm_bt_kernel(
    const unsigned short* __restrict__ A, const unsigned short* __restrict__ Bt,
    const float* __restrict__ bias, unsigned short* __restrict__ Qb,
    unsigned short* __restrict__ Kb, unsigned short* __restrict__ Vt,
    float* __restrict__ Cout) {
  const int K = 1024;
  __shared__ __align__(16) unsigned short As[128 * 32];
  __shared__ __align__(16) unsigned short Bs[128 * 32];
  const int tid = threadIdx.x;
  const int m0 = blockIdx.x * 128, n0 = blockIdx.y * 128;
  const int wid = tid >> 6, lane = tid & 63;
  const int wr = wid >> 1, wc = wid & 1;
  const int l15 = lane & 15, lg = lane >> 4;

  // per-lane global staging coords (phase 0: rows 0..63, phase 1: rows 64..127)
  const int r0 = tid >> 2, kk0 = (tid & 3) * 8;
  const int r1 = (256 + tid) >> 2, kk1 = (tid & 3) * 8;

  f32x4 acc[4][4];
#pragma unroll
  for (int m = 0; m < 4; ++m)
#pragma unroll
    for (int n = 0; n < 4; ++n) acc[m][n] = (f32x4){0.f, 0.f, 0.f, 0.f};

  for (int k0 = 0; k0 < K; k0 += 32) {
    __syncthreads();
    {
      char* asb = (char*)As + (wid << 10);
      char* bsb = (char*)Bs + (wid << 10);
      __builtin_amdgcn_global_load_lds(
          GLB_AS1(&A[(size_t)(m0 + r0) * K + k0 + kk0]), LDS_AS3(asb), 16, 0, 0);
      __builtin_amdgcn_global_load_lds(
          GLB_AS1(&Bt[(size_t)(n0 + r0) * K + k0 + kk0]), LDS_AS3(bsb), 16, 0, 0);
      __builtin_amdgcn_global_load_lds(
          GLB_AS1(&A[(size_t)(m0 + r1) * K + k0 + kk1]), LDS_AS3(asb + 4096), 16, 0, 0);
      __builtin_amdgcn_global_load_lds(
          GLB_AS1(&Bt[(size_t)(n0 + r1) * K + k0 + kk1]), LDS_AS3(bsb + 4096), 16, 0, 0);
    }
    __syncthreads();
    bf16x8 af[4], bf[4];
#pragma unroll
    for (int m = 0; m < 4; ++m)
      af[m] = *(bf16x8*)&As[(wr * 64 + m * 16 + l15) * 32 + lg * 8];
#pragma unroll
    for (int n = 0; n < 4; ++n)
      bf[n] = *(bf16x8*)&Bs[(wc * 64 + n * 16 + l15) * 32 + lg * 8];
#pragma unroll
    for (int m = 0; m < 4; ++m)
#pragma unroll
      for (int n = 0; n < 4; ++n)
        acc[m][n] =
            __builtin_amdgcn_mfma_f32_16x16x32_bf16(af[m], bf[n], acc[m][n], 0, 0, 0);
  }

  // epilogue: C/D layout col = lane&15, row = (lane>>4)*4 + reg  [HW-verified]
#pragma unroll
  for (int m = 0; m < 4; ++m) {
#pragma unroll
    for (int n = 0; n < 4; ++n) {
#pragma unroll
      for (int r = 0; r < 4; ++r) {
        int R = m0 + wr * 64 + m * 16 + lg * 4 + r;
        int c = n0 + wc * 64 + n * 16 + l15;
        float val = acc[m][n][r] + bias[c];
        if (MODE == 0) {
          int b = R / S_, s = R % S_;
          int hh = c / 192, rr = c % 192;
          int sel = rr >> 6, dd = rr & 63;
          unsigned short bv = f32_to_bf16(val);
          if (sel == 0) {
            Qb[((size_t)(b * H_ + hh) * S_ + s) * HD_ + dd] = bv;
          } else if (sel == 1) {
            Kb[((size_t)(b * H_ + hh) * S_ + s) * HD_ + dd] = bv;
          } else {
            // V stored transposed: Vt[b,h,dd,s]
            Vt[((size_t)(b * H_ + hh) * HD_ + dd) * S_ + s] = bv;
          }
        } else {
          Cout[(size_t)R * D_ + c] = val;
        }
      }
    }
  }
}

// ---------------- XL-bias via MFMA, b-shared (2x waste) ---------------------
// grid (h=16, itile=24), 512 threads (8 waves). Wave w handles il = 2w, 2w+1.
// For fixed (il, jH): table row r = il*24 + jH + (384 - 24h - itile) is shared
// by all 8 batches -> MFMA A-rows = b. Writes bias f32 into the attention
// region of d_out at its final slot (attn2 reads then overwrites with probs).
__global__ __launch_bounds__(512) void bias_kernel(
    const unsigned short* __restrict__ Qb, const unsigned short* __restrict__ Tb,
    float* __restrict__ biasout) {
  const int hh = blockIdx.x;     // 0..15
  const int itile = blockIdx.y;  // 0..23
  const int tid = threadIdx.x;
  const int wid = tid >> 6, lane = tid & 63;
  const int l15 = lane & 15, lg = lane >> 4;
  const int C = 384 - 24 * hh - itile;
  const int i0 = itile * 16;

#pragma unroll
  for (int t = 0; t < 2; ++t) {
    const int il = wid * 2 + t;
    const int i = i0 + il;
    // A-frag: row = b (lanes 8..15 duplicate b&7), k = d
    const int b8 = l15 & 7;
    const size_t qaddr = ((size_t)(b8 * H_ + hh) * S_ + i) * HD_ + lg * 8;
    bf16x8 a0 = *(const bf16x8*)&Qb[qaddr];        // d in [0,32)
    bf16x8 a1 = *(const bf16x8*)&Qb[qaddr + 32];   // d in [32,64)
    const int rbase = il * 24 + C;
#pragma unroll 4
    for (int jH = 0; jH < 24; ++jH) {
      const unsigned short* trow = Tb + (size_t)(rbase + jH) * D_;
      // B-frag: col = jL (l15), k = d : T[r, jL*64 + d]
      bf16x8 b0 = *(const bf16x8*)&trow[l15 * 64 + lg * 8];
      bf16x8 b1 = *(const bf16x8*)&trow[l15 * 64 + 32 + lg * 8];
      f32x4 d = {0.f, 0.f, 0.f, 0.f};
      d = __builtin_amdgcn_mfma_f32_16x16x32_bf16(a0, b0, d, 0, 0, 0);
      d = __builtin_amdgcn_mfma_f32_16x16x32_bf16(a1, b1, d, 0, 0, 0);
      if (lg < 2) {  // D rows = b = lg*4+rr, valid b<8; cols = jL = l15
#pragma unroll
        for (int rr = 0; rr < 4; ++rr) {
          const int b = lg * 4 + rr;
          biasout[((size_t)(b * H_ + hh) * S_ + i) * S_ + jH * 16 + l15] = d[rr];
        }
      }
    }
  }
}

// ---------------- fused QK^T(+bias) -> softmax -> PV, all MFMA --------------
// grid (b*h=128, itile=24), 256 threads (4 waves).
__global__ __launch_bounds__(256) void attn2_kernel(
    const unsigned short* __restrict__ Qb, const unsigned short* __restrict__ Kb,
    const unsigned short* __restrict__ Vt, float* __restrict__ attn_out,
    unsigned short* __restrict__ Vals) {
  __shared__ float lgs[16][392];          // logits f32 (+8 pad)
  __shared__ unsigned short pb[16][392];  // probs bf16 (+8 pad)
  const int bh = blockIdx.x;
  const int itile = blockIdx.y;
  const int i0 = itile * 16;
  const size_t base = (size_t)bh * (S_ * HD_);
  const int tid = threadIdx.x, wid = tid >> 6, lane = tid & 63;
  const int l15 = lane & 15, lg = lane >> 4;

  // Q A-frags: row = il (l15), k = d
  const size_t qaddr = base + (size_t)(i0 + l15) * HD_ + lg * 8;
  bf16x8 qa0 = *(const bf16x8*)&Qb[qaddr];
  bf16x8 qa1 = *(const bf16x8*)&Qb[qaddr + 32];

  // ---- QK^T + bias: wave handles jH = wid*6 .. wid*6+5
#pragma unroll
  for (int t = 0; t < 6; ++t) {
    const int jH = wid * 6 + t;
    const int j0 = jH * 16;
    const size_t kaddr = base + (size_t)(j0 + l15) * HD_ + lg * 8;
    bf16x8 kb0 = *(const bf16x8*)&Kb[kaddr];
    bf16x8 kb1 = *(const bf16x8*)&Kb[kaddr + 32];
    f32x4 d = {0.f, 0.f, 0.f, 0.f};
    d = __builtin_amdgcn_mfma_f32_16x16x32_bf16(qa0, kb0, d, 0, 0, 0);
    d = __builtin_amdgcn_mfma_f32_16x16x32_bf16(qa1, kb1, d, 0, 0, 0);
#pragma unroll
    for (int rr = 0; rr < 4; ++rr) {  // D: row = il = lg*4+rr, col = jL = l15
      const int il = lg * 4 + rr;
      float bv = attn_out[((size_t)bh * S_ + i0 + il) * S_ + j0 + l15];
      lgs[il][j0 + l15] = d[rr] * 0.125f + bv;
    }
  }
  __syncthreads();

  // ---- softmax (16 lanes per row) + write probs f32 to out, bf16 to LDS
  {
    const int row = tid >> 4, l16 = tid & 15;
    float m = -1e30f;
    for (int j = l16; j < S_; j += 16) m = fmaxf(m, lgs[row][j]);
#pragma unroll
    for (int o = 8; o; o >>= 1) m = fmaxf(m, __shfl_xor(m, o, 16));
    float s = 0.f;
    for (int j = l16; j < S_; j += 16) {
      float e = __expf(lgs[row][j] - m);
      lgs[row][j] = e;
      s += e;
    }
#pragma unroll
    for (int o = 8; o; o >>= 1) s += __shfl_xor(s, o, 16);
    const float inv = 1.0f / s;
    float* ao = attn_out + ((size_t)bh * S_ + i0 + row) * S_;
    for (int j = l16; j < S_; j += 16) {
      float p = lgs[row][j] * inv;
      ao[j] = p;
      pb[row][j] = f32_to_bf16(p);
    }
  }
  __syncthreads();

  // ---- PV: wave wid owns d-tile d0 = wid*16. A = probs(16x384), B = Vt slice
  {
    const int d0 = wid * 16;
    f32x4 acc = {0.f, 0.f, 0.f, 0.f};
#pragma unroll 4
    for (int kc = 0; kc < 12; ++kc) {
      bf16x8 pa = *(const bf16x8*)&pb[l15][kc * 32 + lg * 8];
      bf16x8 vb = *(const bf16x8*)&Vt[base + (size_t)(d0 + l15) * S_ + kc * 32 + lg * 8];
      acc = __builtin_amdgcn_mfma_f32_16x16x32_bf16(pa, vb, acc, 0, 0, 0);
    }
    const int b = bh >> 4, hh = bh & 15;
#pragma unroll
    for (int rr = 0; rr < 4; ++rr) {
      const int il = lg * 4 + rr;
      Vals[((size_t)(b * S_ + i0 + il)) * D_ + hh * HD_ + d0 + l15] =
          f32_to_bf16(acc[rr]);
    }
  }
}

// ---------------------------------------------------------------------------
extern "C" void kernel_launch(void* const* d_in, const int* in_sizes, int n_in,
                              void* d_out, int out_size, void* d_ws,
                              size_t ws_size, hipStream_t stream) {
  (void)in_sizes; (void)n_in; (void)out_size; (void)ws_size;
  const float* x     = (const float*)d_in[0];  // (8,384,1024)
  const float* qkv_w = (const float*)d_in[1];  // (1024,3072)
  const float* qkv_b = (const float*)d_in[2];  // (3072,)
  const float* out_w = (const float*)d_in[3];  // (1024,1024)
  const float* out_b = (const float*)d_in[4];  // (1024,)
  const float* rpe   = (const float*)d_in[5];  // (1023,1024)

  float* out  = (float*)d_out;        // 3145728 f32
  float* attn = out + 3145728;        // 18874368 f32 (used as bias scratch first)

  unsigned short* ws  = (unsigned short*)d_ws;
  unsigned short* xb  = ws;                 // 3072*1024
  unsigned short* Wt  = xb + 3145728;       // 3072*1024 (qkv_w^T)
  unsigned short* Wot = Wt + 3145728;       // 1024*1024 (out_w^T)
  unsigned short* Tb  = Wot + 1048576;      // 1023*1024
  unsigned short* Qb  = Tb + 1047552;       // (b,h,s,hd)
  unsigned short* Kb  = Qb + 3145728;       // (b,h,s,hd)
  unsigned short* Vt  = Kb + 3145728;       // (b,h,hd,s)  transposed V
  unsigned short* Vals = Vt + 3145728;      // (b*s, 1024) bf16

  // 1) casts / transposes
  cast_kernel<<<3072, 256, 0, stream>>>(x, xb, 786432);
  cast_kernel<<<1023, 256, 0, stream>>>(rpe, Tb, 261888);
  transpose_cast_kernel<<<dim3(96, 32), dim3(32, 8), 0, stream>>>(qkv_w, Wt, 1024, 3072);
  transpose_cast_kernel<<<dim3(32, 32), dim3(32, 8), 0, stream>>>(out_w, Wot, 1024, 1024);

  // 2) QKV projection (M=3072, N=3072); V written transposed
  gemm_bt_kernel<0><<<dim3(24, 24), 256, 0, stream>>>(xb, Wt, qkv_b, Qb, Kb, Vt, nullptr);

  // 3) XL relative bias (MFMA, b-shared) -> staged f32 in attn-out slots
  bias_kernel<<<dim3(16, 24), 512, 0, stream>>>(Qb, Tb, attn);

  // 4) fused QK^T(+bias) -> softmax -> PV (all MFMA)
  attn2_kernel<<<dim3(128, 24), 256, 0, stream>>>(Qb, Kb, Vt, attn, Vals);

  // 5) output projection (M=3072, N=1024)
  gemm_bt_kernel<1><<<dim3(24, 8), 256, 0, stream>>>(Vals, Wot, out_b, nullptr, nullptr, nullptr, out);
}

// Round 5
// 265.170 us; speedup vs baseline: 3.0735x; 1.0280x over previous
//
#include <hip/hip_runtime.h>

// Problem constants: B=8, S=384, D=1024, H=16, hd=64
#define S_ 384
#define D_ 1024
#define H_ 16
#define HD_ 64

typedef short bf16x8 __attribute__((ext_vector_type(8)));
typedef float f32x4 __attribute__((ext_vector_type(4)));

#define LDS_AS3(p) ((__attribute__((address_space(3))) unsigned int*)(p))
#define GLB_AS1(p) ((const __attribute__((address_space(1))) unsigned int*)(p))

__device__ __forceinline__ unsigned short f32_to_bf16(float f) {
  unsigned u = __float_as_uint(f);
  u += 0x7FFFu + ((u >> 16) & 1u);   // round-to-nearest-even
  return (unsigned short)(u >> 16);
}
__device__ __forceinline__ float bf16_to_f32(unsigned short h) {
  return __uint_as_float(((unsigned)h) << 16);
}

// ---------------- cast f32 -> bf16 (element-wise, float4 vectorized) --------
__global__ void cast_kernel(const float* __restrict__ src,
                            unsigned short* __restrict__ dst, int n4) {
  int i = blockIdx.x * blockDim.x + threadIdx.x;
  if (i >= n4) return;
  float4 v = ((const float4*)src)[i];
  ushort4 o;
  o.x = f32_to_bf16(v.x); o.y = f32_to_bf16(v.y);
  o.z = f32_to_bf16(v.z); o.w = f32_to_bf16(v.w);
  ((ushort4*)dst)[i] = o;
}

// ---------------- transpose + cast: W[K][N] f32 -> Wt[N][K] bf16 ------------
__global__ void transpose_cast_kernel(const float* __restrict__ W,
                                      unsigned short* __restrict__ Wt,
                                      int K, int N) {
  __shared__ float tile[32][33];
  int n0 = blockIdx.x * 32, k0 = blockIdx.y * 32;
  int tx = threadIdx.x, ty = threadIdx.y;  // (32, 8)
#pragma unroll
  for (int yy = 0; yy < 32; yy += 8)
    tile[ty + yy][tx] = W[(size_t)(k0 + ty + yy) * N + n0 + tx];
  __syncthreads();
#pragma unroll
  for (int yy = 0; yy < 32; yy += 8)
    Wt[(size_t)(n0 + ty + yy) * K + k0 + tx] = f32_to_bf16(tile[tx][ty + yy]);
}

// ---------------- bf16 MFMA GEMM: C[M][N] = A[M][1024] * Bt[N][1024]^T ------
// 128x128 tile, 4 waves (2x2 of 64x64), BK=32, global_load_lds staging (m97).
// LDS slot byte = tt*16 (linear in thread order) == wave base + lane*16.
// MODE 0: QKV epilogue (scatter to Qb/Kb bf16, V transposed to Vt, +qkv_b)
// MODE 1: out-proj epilogue (f32 to Cout, +out_b)
template <int MODE>
__global__ __launch_bounds__(256) void gemm_bt_kernel(
    const unsigned short* __restrict__ A, const unsigned short* __restrict__ Bt,
    const float* __restrict__ bias, unsigned short* __restrict__ Qb,
    unsigned short* __restrict__ Kb, unsigned short* __restrict__ Vt,
    float* __restrict__ Cout) {
  const int K = 1024;
  __shared__ __align__(16) unsigned short As[128 * 32];
  __shared__ __align__(16) unsigned short Bs[128 * 32];
  const int tid = threadIdx.x;
  const int m0 = blockIdx.x * 128, n0 = blockIdx.y * 128;
  const int wid = tid >> 6, lane = tid & 63;
  const int wr = wid >> 1, wc = wid & 1;
  const int l15 = lane & 15, lg = lane >> 4;

  // per-lane global staging coords (phase 0: rows 0..63, phase 1: rows 64..127)
  const int r0 = tid >> 2, kk0 = (tid & 3) * 8;
  const int r1 = (256 + tid) >> 2, kk1 = (tid & 3) * 8;

  f32x4 acc[4][4];
#pragma unroll
  for (int m = 0; m < 4; ++m)
#pragma unroll
    for (int n = 0; n < 4; ++n) acc[m][n] = (f32x4){0.f, 0.f, 0.f, 0.f};

  for (int k0 = 0; k0 < K; k0 += 32) {
    __syncthreads();
    {
      char* asb = (char*)As + (wid << 10);
      char* bsb = (char*)Bs + (wid << 10);
      __builtin_amdgcn_global_load_lds(
          GLB_AS1(&A[(size_t)(m0 + r0) * K + k0 + kk0]), LDS_AS3(asb), 16, 0, 0);
      __builtin_amdgcn_global_load_lds(
          GLB_AS1(&Bt[(size_t)(n0 + r0) * K + k0 + kk0]), LDS_AS3(bsb), 16, 0, 0);
      __builtin_amdgcn_global_load_lds(
          GLB_AS1(&A[(size_t)(m0 + r1) * K + k0 + kk1]), LDS_AS3(asb + 4096), 16, 0, 0);
      __builtin_amdgcn_global_load_lds(
          GLB_AS1(&Bt[(size_t)(n0 + r1) * K + k0 + kk1]), LDS_AS3(bsb + 4096), 16, 0, 0);
    }
    __syncthreads();
    bf16x8 af[4], bf[4];
#pragma unroll
    for (int m = 0; m < 4; ++m)
      af[m] = *(bf16x8*)&As[(wr * 64 + m * 16 + l15) * 32 + lg * 8];
#pragma unroll
    for (int n = 0; n < 4; ++n)
      bf[n] = *(bf16x8*)&Bs[(wc * 64 + n * 16 + l15) * 32 + lg * 8];
#pragma unroll
    for (int m = 0; m < 4; ++m)
#pragma unroll
      for (int n = 0; n < 4; ++n)
        acc[m][n] =
            __builtin_amdgcn_mfma_f32_16x16x32_bf16(af[m], bf[n], acc[m][n], 0, 0, 0);
  }

  // epilogue: C/D layout col = lane&15, row = (lane>>4)*4 + reg  [HW-verified]
#pragma unroll
  for (int m = 0; m < 4; ++m) {
#pragma unroll
    for (int n = 0; n < 4; ++n) {
#pragma unroll
      for (int r = 0; r < 4; ++r) {
        int R = m0 + wr * 64 + m * 16 + lg * 4 + r;
        int c = n0 + wc * 64 + n * 16 + l15;
        float val = acc[m][n][r] + bias[c];
        if (MODE == 0) {
          int b = R / S_, s = R % S_;
          int hh = c / 192, rr = c % 192;
          int sel = rr >> 6, dd = rr & 63;
          unsigned short bv = f32_to_bf16(val);
          if (sel == 0) {
            Qb[((size_t)(b * H_ + hh) * S_ + s) * HD_ + dd] = bv;
          } else if (sel == 1) {
            Kb[((size_t)(b * H_ + hh) * S_ + s) * HD_ + dd] = bv;
          } else {
            // V stored transposed: Vt[b,h,dd,s]
            Vt[((size_t)(b * H_ + hh) * HD_ + dd) * S_ + s] = bv;
          }
        } else {
          Cout[(size_t)R * D_ + c] = val;
        }
      }
    }
  }
}

// ---------------- XL-bias via MFMA, b-shared (2x waste) ---------------------
// grid (h=16, itile=24, jz=3), 512 threads (8 waves). Wave w: il = 2w, 2w+1;
// block z covers jH = 8z .. 8z+7. For fixed (il, jH): table row
// r = il*24 + jH + (384 - 24h - itile) is shared by all 8 batches ->
// MFMA A-rows = b. Bias staged bf16 into workspace (read by attn2).
__global__ __launch_bounds__(512) void bias_kernel(
    const unsigned short* __restrict__ Qb, const unsigned short* __restrict__ Tb,
    unsigned short* __restrict__ biasout) {
  const int hh = blockIdx.x;     // 0..15
  const int itile = blockIdx.y;  // 0..23
  const int jz = blockIdx.z;     // 0..2
  const int tid = threadIdx.x;
  const int wid = tid >> 6, lane = tid & 63;
  const int l15 = lane & 15, lg = lane >> 4;
  const int C = 384 - 24 * hh - itile;
  const int i0 = itile * 16;

#pragma unroll
  for (int t = 0; t < 2; ++t) {
    const int il = wid * 2 + t;
    const int i = i0 + il;
    // A-frag: row = b (lanes 8..15 duplicate b&7), k = d
    const int b8 = l15 & 7;
    const size_t qaddr = ((size_t)(b8 * H_ + hh) * S_ + i) * HD_ + lg * 8;
    bf16x8 a0 = *(const bf16x8*)&Qb[qaddr];        // d in [0,32)
    bf16x8 a1 = *(const bf16x8*)&Qb[qaddr + 32];   // d in [32,64)
    const int rbase = il * 24 + C;
#pragma unroll 4
    for (int jH = jz * 8; jH < jz * 8 + 8; ++jH) {
      const unsigned short* trow = Tb + (size_t)(rbase + jH) * D_;
      // B-frag: col = jL (l15), k = d : T[r, jL*64 + d]
      bf16x8 b0 = *(const bf16x8*)&trow[l15 * 64 + lg * 8];
      bf16x8 b1 = *(const bf16x8*)&trow[l15 * 64 + 32 + lg * 8];
      f32x4 d = {0.f, 0.f, 0.f, 0.f};
      d = __builtin_amdgcn_mfma_f32_16x16x32_bf16(a0, b0, d, 0, 0, 0);
      d = __builtin_amdgcn_mfma_f32_16x16x32_bf16(a1, b1, d, 0, 0, 0);
      if (lg < 2) {  // D rows = b = lg*4+rr, valid b<8; cols = jL = l15
#pragma unroll
        for (int rr = 0; rr < 4; ++rr) {
          const int b = lg * 4 + rr;
          biasout[((size_t)(b * H_ + hh) * S_ + i) * S_ + jH * 16 + l15] =
              f32_to_bf16(d[rr]);
        }
      }
    }
  }
}

// ---------------- fused QK^T(+bias) -> softmax -> PV, all MFMA --------------
// grid (b*h=128, itile=24), 256 threads (4 waves).
__global__ __launch_bounds__(256) void attn2_kernel(
    const unsigned short* __restrict__ Qb, const unsigned short* __restrict__ Kb,
    const unsigned short* __restrict__ Vt, const unsigned short* __restrict__ Bias,
    float* __restrict__ attn_out, unsigned short* __restrict__ Vals) {
  __shared__ float lgs[16][392];          // logits f32 (+8 pad)
  __shared__ unsigned short pb[16][392];  // probs bf16 (+8 pad)
  const int bh = blockIdx.x;
  const int itile = blockIdx.y;
  const int i0 = itile * 16;
  const size_t base = (size_t)bh * (S_ * HD_);
  const int tid = threadIdx.x, wid = tid >> 6, lane = tid & 63;
  const int l15 = lane & 15, lg = lane >> 4;

  // Q A-frags: row = il (l15), k = d
  const size_t qaddr = base + (size_t)(i0 + l15) * HD_ + lg * 8;
  bf16x8 qa0 = *(const bf16x8*)&Qb[qaddr];
  bf16x8 qa1 = *(const bf16x8*)&Qb[qaddr + 32];

  // ---- QK^T + bias: wave handles jH = wid*6 .. wid*6+5
#pragma unroll
  for (int t = 0; t < 6; ++t) {
    const int jH = wid * 6 + t;
    const int j0 = jH * 16;
    const size_t kaddr = base + (size_t)(j0 + l15) * HD_ + lg * 8;
    bf16x8 kb0 = *(const bf16x8*)&Kb[kaddr];
    bf16x8 kb1 = *(const bf16x8*)&Kb[kaddr + 32];
    f32x4 d = {0.f, 0.f, 0.f, 0.f};
    d = __builtin_amdgcn_mfma_f32_16x16x32_bf16(qa0, kb0, d, 0, 0, 0);
    d = __builtin_amdgcn_mfma_f32_16x16x32_bf16(qa1, kb1, d, 0, 0, 0);
#pragma unroll
    for (int rr = 0; rr < 4; ++rr) {  // D: row = il = lg*4+rr, col = jL = l15
      const int il = lg * 4 + rr;
      float bv = bf16_to_f32(Bias[((size_t)bh * S_ + i0 + il) * S_ + j0 + l15]);
      lgs[il][j0 + l15] = d[rr] * 0.125f + bv;
    }
  }
  __syncthreads();

  // ---- softmax (16 lanes per row) + write probs f32 to out, bf16 to LDS
  {
    const int row = tid >> 4, l16 = tid & 15;
    float m = -1e30f;
    for (int j = l16; j < S_; j += 16) m = fmaxf(m, lgs[row][j]);
#pragma unroll
    for (int o = 8; o; o >>= 1) m = fmaxf(m, __shfl_xor(m, o, 16));
    float s = 0.f;
    for (int j = l16; j < S_; j += 16) {
      float e = __expf(lgs[row][j] - m);
      lgs[row][j] = e;
      s += e;
    }
#pragma unroll
    for (int o = 8; o; o >>= 1) s += __shfl_xor(s, o, 16);
    const float inv = 1.0f / s;
    float* ao = attn_out + ((size_t)bh * S_ + i0 + row) * S_;
    for (int j = l16; j < S_; j += 16) {
      float p = lgs[row][j] * inv;
      ao[j] = p;
      pb[row][j] = f32_to_bf16(p);
    }
  }
  __syncthreads();

  // ---- PV: wave wid owns d-tile d0 = wid*16. A = probs(16x384), B = Vt slice
  {
    const int d0 = wid * 16;
    f32x4 acc = {0.f, 0.f, 0.f, 0.f};
#pragma unroll 4
    for (int kc = 0; kc < 12; ++kc) {
      bf16x8 pa = *(const bf16x8*)&pb[l15][kc * 32 + lg * 8];
      bf16x8 vb = *(const bf16x8*)&Vt[base + (size_t)(d0 + l15) * S_ + kc * 32 + lg * 8];
      acc = __builtin_amdgcn_mfma_f32_16x16x32_bf16(pa, vb, acc, 0, 0, 0);
    }
    const int b = bh >> 4, hh = bh & 15;
#pragma unroll
    for (int rr = 0; rr < 4; ++rr) {
      const int il = lg * 4 + rr;
      Vals[((size_t)(b * S_ + i0 + il)) * D_ + hh * HD_ + d0 + l15] =
          f32_to_bf16(acc[rr]);
    }
  }
}

// ---------------------------------------------------------------------------
extern "C" void kernel_launch(void* const* d_in, const int* in_sizes, int n_in,
                              void* d_out, int out_size, void* d_ws,
                              size_t ws_size, hipStream_t stream) {
  (void)in_sizes; (void)n_in; (void)out_size; (void)ws_size;
  const float* x     = (const float*)d_in[0];  // (8,384,1024)
  const float* qkv_w = (const float*)d_in[1];  // (1024,3072)
  const float* qkv_b = (const float*)d_in[2];  // (3072,)
  const float* out_w = (const float*)d_in[3];  // (1024,1024)
  const float* out_b = (const float*)d_in[4];  // (1024,)
  const float* rpe   = (const float*)d_in[5];  // (1023,1024)

  float* out  = (float*)d_out;        // 3145728 f32
  float* attn = out + 3145728;        // 18874368 f32 (probs, written by attn2)

  unsigned short* ws  = (unsigned short*)d_ws;
  unsigned short* xb  = ws;                 // 3072*1024
  unsigned short* Wt  = xb + 3145728;       // 3072*1024 (qkv_w^T)
  unsigned short* Wot = Wt + 3145728;       // 1024*1024 (out_w^T)
  unsigned short* Tb  = Wot + 1048576;      // 1023*1024
  unsigned short* Qb  = Tb + 1047552;       // (b,h,s,hd)
  unsigned short* Kb  = Qb + 3145728;       // (b,h,s,hd)
  unsigned short* Vt  = Kb + 3145728;       // (b,h,hd,s)  transposed V
  unsigned short* Vals = Vt + 3145728;      // (b*s, 1024) bf16
  unsigned short* Bias = Vals + 3145728;    // (b,h,s,s) bf16 staged XL bias

  // 1) casts / transposes
  cast_kernel<<<3072, 256, 0, stream>>>(x, xb, 786432);
  cast_kernel<<<1023, 256, 0, stream>>>(rpe, Tb, 261888);
  transpose_cast_kernel<<<dim3(96, 32), dim3(32, 8), 0, stream>>>(qkv_w, Wt, 1024, 3072);
  transpose_cast_kernel<<<dim3(32, 32), dim3(32, 8), 0, stream>>>(out_w, Wot, 1024, 1024);

  // 2) QKV projection (M=3072, N=3072); V written transposed
  gemm_bt_kernel<0><<<dim3(24, 24), 256, 0, stream>>>(xb, Wt, qkv_b, Qb, Kb, Vt, nullptr);

  // 3) XL relative bias (MFMA, b-shared) -> bf16 workspace
  bias_kernel<<<dim3(16, 24, 3), 512, 0, stream>>>(Qb, Tb, Bias);

  // 4) fused QK^T(+bias) -> softmax -> PV (all MFMA)
  attn2_kernel<<<dim3(128, 24), 256, 0, stream>>>(Qb, Kb, Vt, Bias, attn, Vals);

  // 5) output projection (M=3072, N=1024)
  gemm_bt_kernel<1><<<dim3(24, 8), 256, 0, stream>>>(Vals, Wot, out_b, nullptr, nullptr, nullptr, out);
}

// Round 6
// 264.603 us; speedup vs baseline: 3.0801x; 1.0021x over previous
//
#include <hip/hip_runtime.h>

// Problem constants: B=8, S=384, D=1024, H=16, hd=64
#define S_ 384
#define D_ 1024
#define H_ 16
#define HD_ 64

typedef short bf16x8 __attribute__((ext_vector_type(8)));
typedef float f32x4 __attribute__((ext_vector_type(4)));

#define LDS_AS3(p) ((__attribute__((address_space(3))) unsigned int*)(p))
#define GLB_AS1(p) ((const __attribute__((address_space(1))) unsigned int*)(p))

__device__ __forceinline__ unsigned short f32_to_bf16(float f) {
  unsigned u = __float_as_uint(f);
  u += 0x7FFFu + ((u >> 16) & 1u);   // round-to-nearest-even
  return (unsigned short)(u >> 16);
}
__device__ __forceinline__ float bf16_to_f32(unsigned short h) {
  return __uint_as_float(((unsigned)h) << 16);
}

// ---------------- cast f32 -> bf16 (element-wise, float4 vectorized) --------
__global__ void cast_kernel(const float* __restrict__ src,
                            unsigned short* __restrict__ dst, int n4) {
  int i = blockIdx.x * blockDim.x + threadIdx.x;
  if (i >= n4) return;
  float4 v = ((const float4*)src)[i];
  ushort4 o;
  o.x = f32_to_bf16(v.x); o.y = f32_to_bf16(v.y);
  o.z = f32_to_bf16(v.z); o.w = f32_to_bf16(v.w);
  ((ushort4*)dst)[i] = o;
}

// ---------------- transpose + cast: W[K][N] f32 -> Wt[N][K] bf16 ------------
__global__ void transpose_cast_kernel(const float* __restrict__ W,
                                      unsigned short* __restrict__ Wt,
                                      int K, int N) {
  __shared__ float tile[32][33];
  int n0 = blockIdx.x * 32, k0 = blockIdx.y * 32;
  int tx = threadIdx.x, ty = threadIdx.y;  // (32, 8)
#pragma unroll
  for (int yy = 0; yy < 32; yy += 8)
    tile[ty + yy][tx] = W[(size_t)(k0 + ty + yy) * N + n0 + tx];
  __syncthreads();
#pragma unroll
  for (int yy = 0; yy < 32; yy += 8)
    Wt[(size_t)(n0 + ty + yy) * K + k0 + tx] = f32_to_bf16(tile[tx][ty + yy]);
}

// ---------------- bf16 MFMA GEMM: C[M][N] = A[M][1024] * Bt[N][1024]^T ------
// 128x128 tile, 4 waves (2x2 of 64x64), BK=32, global_load_lds staging (m97).
// MODE 0: QKV epilogue (scatter to Qb/Kb bf16, V transposed to Vt, +qkv_b)
// MODE 1: out-proj epilogue (f32 to Cout, +out_b)
template <int MODE>
__global__ __launch_bounds__(256) void gemm_bt_kernel(
    const unsigned short* __restrict__ A, const unsigned short* __restrict__ Bt,
    const float* __restrict__ bias, unsigned short* __restrict__ Qb,
    unsigned short* __restrict__ Kb, unsigned short* __restrict__ Vt,
    float* __restrict__ Cout) {
  const int K = 1024;
  __shared__ __align__(16) unsigned short As[128 * 32];
  __shared__ __align__(16) unsigned short Bs[128 * 32];
  const int tid = threadIdx.x;
  const int m0 = blockIdx.x * 128, n0 = blockIdx.y * 128;
  const int wid = tid >> 6, lane = tid & 63;
  const int wr = wid >> 1, wc = wid & 1;
  const int l15 = lane & 15, lg = lane >> 4;

  const int r0 = tid >> 2, kk0 = (tid & 3) * 8;
  const int r1 = (256 + tid) >> 2, kk1 = (tid & 3) * 8;

  f32x4 acc[4][4];
#pragma unroll
  for (int m = 0; m < 4; ++m)
#pragma unroll
    for (int n = 0; n < 4; ++n) acc[m][n] = (f32x4){0.f, 0.f, 0.f, 0.f};

  for (int k0 = 0; k0 < K; k0 += 32) {
    __syncthreads();
    {
      char* asb = (char*)As + (wid << 10);
      char* bsb = (char*)Bs + (wid << 10);
      __builtin_amdgcn_global_load_lds(
          GLB_AS1(&A[(size_t)(m0 + r0) * K + k0 + kk0]), LDS_AS3(asb), 16, 0, 0);
      __builtin_amdgcn_global_load_lds(
          GLB_AS1(&Bt[(size_t)(n0 + r0) * K + k0 + kk0]), LDS_AS3(bsb), 16, 0, 0);
      __builtin_amdgcn_global_load_lds(
          GLB_AS1(&A[(size_t)(m0 + r1) * K + k0 + kk1]), LDS_AS3(asb + 4096), 16, 0, 0);
      __builtin_amdgcn_global_load_lds(
          GLB_AS1(&Bt[(size_t)(n0 + r1) * K + k0 + kk1]), LDS_AS3(bsb + 4096), 16, 0, 0);
    }
    __syncthreads();
    bf16x8 af[4], bf[4];
#pragma unroll
    for (int m = 0; m < 4; ++m)
      af[m] = *(bf16x8*)&As[(wr * 64 + m * 16 + l15) * 32 + lg * 8];
#pragma unroll
    for (int n = 0; n < 4; ++n)
      bf[n] = *(bf16x8*)&Bs[(wc * 64 + n * 16 + l15) * 32 + lg * 8];
#pragma unroll
    for (int m = 0; m < 4; ++m)
#pragma unroll
      for (int n = 0; n < 4; ++n)
        acc[m][n] =
            __builtin_amdgcn_mfma_f32_16x16x32_bf16(af[m], bf[n], acc[m][n], 0, 0, 0);
  }

  // epilogue: C/D layout col = lane&15, row = (lane>>4)*4 + reg  [HW-verified]
#pragma unroll
  for (int m = 0; m < 4; ++m) {
#pragma unroll
    for (int n = 0; n < 4; ++n) {
#pragma unroll
      for (int r = 0; r < 4; ++r) {
        int R = m0 + wr * 64 + m * 16 + lg * 4 + r;
        int c = n0 + wc * 64 + n * 16 + l15;
        float val = acc[m][n][r] + bias[c];
        if (MODE == 0) {
          int b = R / S_, s = R % S_;
          int hh = c / 192, rr = c % 192;
          int sel = rr >> 6, dd = rr & 63;
          unsigned short bv = f32_to_bf16(val);
          if (sel == 0) {
            Qb[((size_t)(b * H_ + hh) * S_ + s) * HD_ + dd] = bv;
          } else if (sel == 1) {
            Kb[((size_t)(b * H_ + hh) * S_ + s) * HD_ + dd] = bv;
          } else {
            Vt[((size_t)(b * H_ + hh) * HD_ + dd) * S_ + s] = bv;
          }
        } else {
          Cout[(size_t)R * D_ + c] = val;
        }
      }
    }
  }
}

// ---------------- XL-bias via MFMA, b-shared (2x waste) ---------------------
// grid (h=16, itile=24, jz=3), 512 threads (8 waves). Wave w: il = 2w, 2w+1;
// block z covers jH = 8z .. 8z+7. Table row r = il*24 + jH + (384-24h-itile)
// shared by all 8 batches -> MFMA A-rows = b. D-fragments go to a per-wave
// LDS buffer [b][j]; a transpose phase then writes fully-coalesced 256B rows
// per (b,i) to the global bf16 Bias tensor (layout (b,h,s,s), read by attn2).
__global__ __launch_bounds__(512) void bias_kernel(
    const unsigned short* __restrict__ Qb, const unsigned short* __restrict__ Tb,
    unsigned short* __restrict__ biasout) {
  __shared__ __align__(16) unsigned short tb[8][8][136];  // [wave][b][j] (+8 pad)
  const int hh = blockIdx.x;     // 0..15
  const int itile = blockIdx.y;  // 0..23
  const int jz = blockIdx.z;     // 0..2
  const int tid = threadIdx.x;
  const int wid = tid >> 6, lane = tid & 63;
  const int l15 = lane & 15, lg = lane >> 4;
  const int C = 384 - 24 * hh - itile;
  const int i0 = itile * 16;

#pragma unroll
  for (int t = 0; t < 2; ++t) {
    const int il = wid * 2 + t;
    const int i = i0 + il;
    // A-frag: row = b (lanes 8..15 duplicate b&7), k = d
    const int b8 = l15 & 7;
    const size_t qaddr = ((size_t)(b8 * H_ + hh) * S_ + i) * HD_ + lg * 8;
    bf16x8 a0 = *(const bf16x8*)&Qb[qaddr];        // d in [0,32)
    bf16x8 a1 = *(const bf16x8*)&Qb[qaddr + 32];   // d in [32,64)
    const int rbase = il * 24 + C;
#pragma unroll
    for (int jrel = 0; jrel < 8; ++jrel) {
      const int jH = jz * 8 + jrel;
      const unsigned short* trow = Tb + (size_t)(rbase + jH) * D_;
      bf16x8 b0 = *(const bf16x8*)&trow[l15 * 64 + lg * 8];
      bf16x8 b1 = *(const bf16x8*)&trow[l15 * 64 + 32 + lg * 8];
      f32x4 d = {0.f, 0.f, 0.f, 0.f};
      d = __builtin_amdgcn_mfma_f32_16x16x32_bf16(a0, b0, d, 0, 0, 0);
      d = __builtin_amdgcn_mfma_f32_16x16x32_bf16(a1, b1, d, 0, 0, 0);
      if (lg < 2) {  // D rows = b = lg*4+rr (valid b<8); cols = jL = l15
#pragma unroll
        for (int rr = 0; rr < 4; ++rr)
          tb[wid][lg * 4 + rr][jrel * 16 + l15] = f32_to_bf16(d[rr]);
      }
    }
    __syncthreads();
    {  // coalesced write: lane -> (b = lane>>3, 32B j-segment)
      const int b = lane >> 3;
      const int jseg = (lane & 7) * 16;
      uint4 v0 = *(const uint4*)&tb[wid][b][jseg];
      uint4 v1 = *(const uint4*)&tb[wid][b][jseg + 8];
      unsigned short* dst =
          &biasout[(((size_t)(b * H_ + hh)) * S_ + i) * S_ + jz * 128 + jseg];
      *(uint4*)dst = v0;
      *(uint4*)&dst[8] = v1;
    }
    __syncthreads();  // tb reused by next t
  }
}

// ---------------- fused QK^T(+bias) -> softmax -> PV, all MFMA --------------
// grid (b*h=128, itile=24), 256 threads (4 waves).
__global__ __launch_bounds__(256) void attn2_kernel(
    const unsigned short* __restrict__ Qb, const unsigned short* __restrict__ Kb,
    const unsigned short* __restrict__ Vt, const unsigned short* __restrict__ Bias,
    float* __restrict__ attn_out, unsigned short* __restrict__ Vals) {
  __shared__ float lgs[16][392];          // logits f32 (+8 pad)
  __shared__ __align__(16) unsigned short pb[16][392];  // bias, then probs bf16
  const int bh = blockIdx.x;
  const int itile = blockIdx.y;
  const int i0 = itile * 16;
  const size_t base = (size_t)bh * (S_ * HD_);
  const int tid = threadIdx.x, wid = tid >> 6, lane = tid & 63;
  const int l15 = lane & 15, lg = lane >> 4;

  // stage bias tile (16x384 bf16 = 12KB) coalesced into pb
  {
    const unsigned short* bsrc = Bias + ((size_t)bh * S_ + i0) * S_;
#pragma unroll
    for (int it = 0; it < 3; ++it) {
      int e = it * 256 + tid;          // 768 chunks of 8 elems
      int row = e / 48, col = (e % 48) * 8;
      *(uint4*)&pb[row][col] = *(const uint4*)&bsrc[(size_t)row * S_ + col];
    }
  }

  // Q A-frags: row = il (l15), k = d
  const size_t qaddr = base + (size_t)(i0 + l15) * HD_ + lg * 8;
  bf16x8 qa0 = *(const bf16x8*)&Qb[qaddr];
  bf16x8 qa1 = *(const bf16x8*)&Qb[qaddr + 32];
  __syncthreads();  // bias staged before epilogue reads

  // ---- QK^T + bias: wave handles jH = wid*6 .. wid*6+5
#pragma unroll
  for (int t = 0; t < 6; ++t) {
    const int jH = wid * 6 + t;
    const int j0 = jH * 16;
    const size_t kaddr = base + (size_t)(j0 + l15) * HD_ + lg * 8;
    bf16x8 kb0 = *(const bf16x8*)&Kb[kaddr];
    bf16x8 kb1 = *(const bf16x8*)&Kb[kaddr + 32];
    f32x4 d = {0.f, 0.f, 0.f, 0.f};
    d = __builtin_amdgcn_mfma_f32_16x16x32_bf16(qa0, kb0, d, 0, 0, 0);
    d = __builtin_amdgcn_mfma_f32_16x16x32_bf16(qa1, kb1, d, 0, 0, 0);
#pragma unroll
    for (int rr = 0; rr < 4; ++rr) {  // D: row = il = lg*4+rr, col = jL = l15
      const int il = lg * 4 + rr;
      lgs[il][j0 + l15] = d[rr] * 0.125f + bf16_to_f32(pb[il][j0 + l15]);
    }
  }
  __syncthreads();

  // ---- softmax (16 lanes per row) + write probs f32 to out, bf16 to LDS
  {
    const int row = tid >> 4, l16 = tid & 15;
    float m = -1e30f;
    for (int j = l16; j < S_; j += 16) m = fmaxf(m, lgs[row][j]);
#pragma unroll
    for (int o = 8; o; o >>= 1) m = fmaxf(m, __shfl_xor(m, o, 16));
    float s = 0.f;
    for (int j = l16; j < S_; j += 16) {
      float e = __expf(lgs[row][j] - m);
      lgs[row][j] = e;
      s += e;
    }
#pragma unroll
    for (int o = 8; o; o >>= 1) s += __shfl_xor(s, o, 16);
    const float inv = 1.0f / s;
    float* ao = attn_out + ((size_t)bh * S_ + i0 + row) * S_;
    for (int j = l16; j < S_; j += 16) {
      float p = lgs[row][j] * inv;
      ao[j] = p;
      pb[row][j] = f32_to_bf16(p);
    }
  }
  __syncthreads();

  // ---- PV: wave wid owns d-tile d0 = wid*16. A = probs(16x384), B = Vt slice
  {
    const int d0 = wid * 16;
    f32x4 acc = {0.f, 0.f, 0.f, 0.f};
#pragma unroll 4
    for (int kc = 0; kc < 12; ++kc) {
      bf16x8 pa = *(const bf16x8*)&pb[l15][kc * 32 + lg * 8];
      bf16x8 vb = *(const bf16x8*)&Vt[base + (size_t)(d0 + l15) * S_ + kc * 32 + lg * 8];
      acc = __builtin_amdgcn_mfma_f32_16x16x32_bf16(pa, vb, acc, 0, 0, 0);
    }
    const int b = bh >> 4, hh = bh & 15;
#pragma unroll
    for (int rr = 0; rr < 4; ++rr) {
      const int il = lg * 4 + rr;
      Vals[((size_t)(b * S_ + i0 + il)) * D_ + hh * HD_ + d0 + l15] =
          f32_to_bf16(acc[rr]);
    }
  }
}

// ---------------------------------------------------------------------------
extern "C" void kernel_launch(void* const* d_in, const int* in_sizes, int n_in,
                              void* d_out, int out_size, void* d_ws,
                              size_t ws_size, hipStream_t stream) {
  (void)in_sizes; (void)n_in; (void)out_size; (void)ws_size;
  const float* x     = (const float*)d_in[0];  // (8,384,1024)
  const float* qkv_w = (const float*)d_in[1];  // (1024,3072)
  const float* qkv_b = (const float*)d_in[2];  // (3072,)
  const float* out_w = (const float*)d_in[3];  // (1024,1024)
  const float* out_b = (const float*)d_in[4];  // (1024,)
  const float* rpe   = (const float*)d_in[5];  // (1023,1024)

  float* out  = (float*)d_out;        // 3145728 f32
  float* attn = out + 3145728;        // 18874368 f32 (probs, written by attn2)

  unsigned short* ws  = (unsigned short*)d_ws;
  unsigned short* xb  = ws;                 // 3072*1024
  unsigned short* Wt  = xb + 3145728;       // 3072*1024 (qkv_w^T)
  unsigned short* Wot = Wt + 3145728;       // 1024*1024 (out_w^T)
  unsigned short* Tb  = Wot + 1048576;      // 1023*1024
  unsigned short* Qb  = Tb + 1047552;       // (b,h,s,hd)
  unsigned short* Kb  = Qb + 3145728;       // (b,h,s,hd)
  unsigned short* Vt  = Kb + 3145728;       // (b,h,hd,s)  transposed V
  unsigned short* Vals = Vt + 3145728;      // (b*s, 1024) bf16
  unsigned short* Bias = Vals + 3145728;    // (b,h,s,s) bf16 staged XL bias

  // 1) casts / transposes
  cast_kernel<<<3072, 256, 0, stream>>>(x, xb, 786432);
  cast_kernel<<<1023, 256, 0, stream>>>(rpe, Tb, 261888);
  transpose_cast_kernel<<<dim3(96, 32), dim3(32, 8), 0, stream>>>(qkv_w, Wt, 1024, 3072);
  transpose_cast_kernel<<<dim3(32, 32), dim3(32, 8), 0, stream>>>(out_w, Wot, 1024, 1024);

  // 2) QKV projection (M=3072, N=3072); V written transposed
  gemm_bt_kernel<0><<<dim3(24, 24), 256, 0, stream>>>(xb, Wt, qkv_b, Qb, Kb, Vt, nullptr);

  // 3) XL relative bias (MFMA, b-shared) -> bf16 workspace, coalesced writes
  bias_kernel<<<dim3(16, 24, 3), 512, 0, stream>>>(Qb, Tb, Bias);

  // 4) fused QK^T(+bias) -> softmax -> PV (all MFMA)
  attn2_kernel<<<dim3(128, 24), 256, 0, stream>>>(Qb, Kb, Vt, Bias, attn, Vals);

  // 5) output projection (M=3072, N=1024)
  gemm_bt_kernel<1><<<dim3(24, 8), 256, 0, stream>>>(Vals, Wot, out_b, nullptr, nullptr, nullptr, out);
}

// Round 7
// 256.041 us; speedup vs baseline: 3.1831x; 1.0334x over previous
//
#include <hip/hip_runtime.h>

// Problem constants: B=8, S=384, D=1024, H=16, hd=64
#define S_ 384
#define D_ 1024
#define H_ 16
#define HD_ 64

typedef short bf16x8 __attribute__((ext_vector_type(8)));
typedef float f32x4 __attribute__((ext_vector_type(4)));

#define LDS_AS3(p) ((__attribute__((address_space(3))) unsigned int*)(p))
#define GLB_AS1(p) ((const __attribute__((address_space(1))) unsigned int*)(p))

__device__ __forceinline__ unsigned short f32_to_bf16(float f) {
  unsigned u = __float_as_uint(f);
  u += 0x7FFFu + ((u >> 16) & 1u);   // round-to-nearest-even
  return (unsigned short)(u >> 16);
}
__device__ __forceinline__ float bf16_to_f32(unsigned short h) {
  return __uint_as_float(((unsigned)h) << 16);
}

// ---------------- fused prep: casts + weight transposes in one launch ------
// sections: [0,3072) x-cast | [3072,4095) rpe-cast | [4095,7167) qkv_w^T
//           | [7167,8191) out_w^T
__global__ __launch_bounds__(256) void prep_kernel(
    const float* __restrict__ x, const float* __restrict__ rpe,
    const float* __restrict__ qkv_w, const float* __restrict__ out_w,
    unsigned short* __restrict__ xb, unsigned short* __restrict__ Tb,
    unsigned short* __restrict__ Wt, unsigned short* __restrict__ Wot) {
  __shared__ float tile[32][33];
  const int bx = blockIdx.x;
  const int tid = threadIdx.x;
  if (bx < 4095) {  // element-wise casts
    const float* src = (bx < 3072) ? x : rpe;
    unsigned short* dst = (bx < 3072) ? xb : Tb;
    int i = (bx < 3072 ? bx : bx - 3072) * 256 + tid;
    float4 v = ((const float4*)src)[i];
    ushort4 o;
    o.x = f32_to_bf16(v.x); o.y = f32_to_bf16(v.y);
    o.z = f32_to_bf16(v.z); o.w = f32_to_bf16(v.w);
    ((ushort4*)dst)[i] = o;
  } else {  // transpose + cast W[K][N] -> Wt[N][K]
    const float* W; unsigned short* WT; int N, bb;
    if (bx < 7167) { W = qkv_w; WT = Wt; N = 3072; bb = bx - 4095; }
    else           { W = out_w; WT = Wot; N = 1024; bb = bx - 7167; }
    const int K = 1024;
    const int nblk = N / 32;
    const int n0 = (bb % nblk) * 32, k0 = (bb / nblk) * 32;
    const int tx = tid & 31, ty = tid >> 5;  // (32, 8)
#pragma unroll
    for (int yy = 0; yy < 32; yy += 8)
      tile[ty + yy][tx] = W[(size_t)(k0 + ty + yy) * N + n0 + tx];
    __syncthreads();
#pragma unroll
    for (int yy = 0; yy < 32; yy += 8)
      WT[(size_t)(n0 + ty + yy) * K + k0 + tx] = f32_to_bf16(tile[tx][ty + yy]);
  }
}

// ---------------- bf16 MFMA GEMM: C[M][N] = A[M][1024] * Bt[N][1024]^T ------
// 128x128 tile, 4 waves (2x2 of 64x64), BK=32, global_load_lds staging (m97).
// MODE 0: QKV epilogue (scatter to Qb/Kb bf16, V transposed to Vt, +qkv_b)
// MODE 1: out-proj epilogue (f32 to Cout, +out_b)
template <int MODE>
__global__ __launch_bounds__(256) void gemm_bt_kernel(
    const unsigned short* __restrict__ A, const unsigned short* __restrict__ Bt,
    const float* __restrict__ bias, unsigned short* __restrict__ Qb,
    unsigned short* __restrict__ Kb, unsigned short* __restrict__ Vt,
    float* __restrict__ Cout) {
  const int K = 1024;
  __shared__ __align__(16) unsigned short As[128 * 32];
  __shared__ __align__(16) unsigned short Bs[128 * 32];
  const int tid = threadIdx.x;
  const int m0 = blockIdx.x * 128, n0 = blockIdx.y * 128;
  const int wid = tid >> 6, lane = tid & 63;
  const int wr = wid >> 1, wc = wid & 1;
  const int l15 = lane & 15, lg = lane >> 4;

  const int r0 = tid >> 2, kk0 = (tid & 3) * 8;
  const int r1 = (256 + tid) >> 2, kk1 = (tid & 3) * 8;

  f32x4 acc[4][4];
#pragma unroll
  for (int m = 0; m < 4; ++m)
#pragma unroll
    for (int n = 0; n < 4; ++n) acc[m][n] = (f32x4){0.f, 0.f, 0.f, 0.f};

  for (int k0 = 0; k0 < K; k0 += 32) {
    __syncthreads();
    {
      char* asb = (char*)As + (wid << 10);
      char* bsb = (char*)Bs + (wid << 10);
      __builtin_amdgcn_global_load_lds(
          GLB_AS1(&A[(size_t)(m0 + r0) * K + k0 + kk0]), LDS_AS3(asb), 16, 0, 0);
      __builtin_amdgcn_global_load_lds(
          GLB_AS1(&Bt[(size_t)(n0 + r0) * K + k0 + kk0]), LDS_AS3(bsb), 16, 0, 0);
      __builtin_amdgcn_global_load_lds(
          GLB_AS1(&A[(size_t)(m0 + r1) * K + k0 + kk1]), LDS_AS3(asb + 4096), 16, 0, 0);
      __builtin_amdgcn_global_load_lds(
          GLB_AS1(&Bt[(size_t)(n0 + r1) * K + k0 + kk1]), LDS_AS3(bsb + 4096), 16, 0, 0);
    }
    __syncthreads();
    bf16x8 af[4], bf[4];
#pragma unroll
    for (int m = 0; m < 4; ++m)
      af[m] = *(bf16x8*)&As[(wr * 64 + m * 16 + l15) * 32 + lg * 8];
#pragma unroll
    for (int n = 0; n < 4; ++n)
      bf[n] = *(bf16x8*)&Bs[(wc * 64 + n * 16 + l15) * 32 + lg * 8];
#pragma unroll
    for (int m = 0; m < 4; ++m)
#pragma unroll
      for (int n = 0; n < 4; ++n)
        acc[m][n] =
            __builtin_amdgcn_mfma_f32_16x16x32_bf16(af[m], bf[n], acc[m][n], 0, 0, 0);
  }

  // epilogue: C/D layout col = lane&15, row = (lane>>4)*4 + reg  [HW-verified]
#pragma unroll
  for (int m = 0; m < 4; ++m) {
#pragma unroll
    for (int n = 0; n < 4; ++n) {
#pragma unroll
      for (int r = 0; r < 4; ++r) {
        int R = m0 + wr * 64 + m * 16 + lg * 4 + r;
        int c = n0 + wc * 64 + n * 16 + l15;
        float val = acc[m][n][r] + bias[c];
        if (MODE == 0) {
          int b = R / S_, s = R % S_;
          int hh = c / 192, rr = c % 192;
          int sel = rr >> 6, dd = rr & 63;
          unsigned short bv = f32_to_bf16(val);
          if (sel == 0) {
            Qb[((size_t)(b * H_ + hh) * S_ + s) * HD_ + dd] = bv;
          } else if (sel == 1) {
            Kb[((size_t)(b * H_ + hh) * S_ + s) * HD_ + dd] = bv;
          } else {
            Vt[((size_t)(b * H_ + hh) * HD_ + dd) * S_ + s] = bv;
          }
        } else {
          Cout[(size_t)R * D_ + c] = val;
        }
      }
    }
  }
}

// ---------------- XL-bias via MFMA, b-shared (2x waste) ---------------------
// grid (h=16, itile=24, jz=3), 512 threads (8 waves). Wave w: il = 2w, 2w+1;
// block z covers jH = 8z..8z+7. Table row r = il*24 + jH + (384-24h-itile)
// shared by all 8 batches -> MFMA A-rows = b. LDS transpose, coalesced writes.
__global__ __launch_bounds__(512) void bias_kernel(
    const unsigned short* __restrict__ Qb, const unsigned short* __restrict__ Tb,
    unsigned short* __restrict__ biasout) {
  __shared__ __align__(16) unsigned short tb[8][8][136];  // [wave][b][j] (+8 pad)
  const int hh = blockIdx.x;     // 0..15
  const int itile = blockIdx.y;  // 0..23
  const int jz = blockIdx.z;     // 0..2
  const int tid = threadIdx.x;
  const int wid = tid >> 6, lane = tid & 63;
  const int l15 = lane & 15, lg = lane >> 4;
  const int C = 384 - 24 * hh - itile;
  const int i0 = itile * 16;

#pragma unroll
  for (int t = 0; t < 2; ++t) {
    const int il = wid * 2 + t;
    const int i = i0 + il;
    const int b8 = l15 & 7;
    const size_t qaddr = ((size_t)(b8 * H_ + hh) * S_ + i) * HD_ + lg * 8;
    bf16x8 a0 = *(const bf16x8*)&Qb[qaddr];        // d in [0,32)
    bf16x8 a1 = *(const bf16x8*)&Qb[qaddr + 32];   // d in [32,64)
    const int rbase = il * 24 + C;
#pragma unroll
    for (int jrel = 0; jrel < 8; ++jrel) {
      const int jH = jz * 8 + jrel;
      const unsigned short* trow = Tb + (size_t)(rbase + jH) * D_;
      bf16x8 b0 = *(const bf16x8*)&trow[l15 * 64 + lg * 8];
      bf16x8 b1 = *(const bf16x8*)&trow[l15 * 64 + 32 + lg * 8];
      f32x4 d = {0.f, 0.f, 0.f, 0.f};
      d = __builtin_amdgcn_mfma_f32_16x16x32_bf16(a0, b0, d, 0, 0, 0);
      d = __builtin_amdgcn_mfma_f32_16x16x32_bf16(a1, b1, d, 0, 0, 0);
      if (lg < 2) {  // D rows = b = lg*4+rr (valid b<8); cols = jL = l15
#pragma unroll
        for (int rr = 0; rr < 4; ++rr)
          tb[wid][lg * 4 + rr][jrel * 16 + l15] = f32_to_bf16(d[rr]);
      }
    }
    __syncthreads();
    {  // coalesced write: lane -> (b = lane>>3, 32B j-segment)
      const int b = lane >> 3;
      const int jseg = (lane & 7) * 16;
      uint4 v0 = *(const uint4*)&tb[wid][b][jseg];
      uint4 v1 = *(const uint4*)&tb[wid][b][jseg + 8];
      unsigned short* dst =
          &biasout[(((size_t)(b * H_ + hh)) * S_ + i) * S_ + jz * 128 + jseg];
      *(uint4*)dst = v0;
      *(uint4*)&dst[8] = v1;
    }
    __syncthreads();  // tb reused by next t
  }
}

// ---------------- fused QK^T(+bias) -> softmax -> PV, 32-row blocks ---------
// grid (b*h=128, it32=12), 256 threads (4 waves). K/V frags reused across the
// two 16-row tiles; bias pre-staged f32 into lgs (logit accumulator); probs
// packed bf16 in-place into the lgs rows (lockstep-safe: ushort j -> f32 j/2).
__global__ __launch_bounds__(256) void attn3_kernel(
    const unsigned short* __restrict__ Qb, const unsigned short* __restrict__ Kb,
    const unsigned short* __restrict__ Vt, const unsigned short* __restrict__ Bias,
    float* __restrict__ attn_out, unsigned short* __restrict__ Vals) {
  __shared__ float lgs[32][408];  // stride 408: softmax 2-way, PV <=4-way banks
  const int bh = blockIdx.x;
  const int it32 = blockIdx.y;
  const int i0 = it32 * 32;
  const size_t base = (size_t)bh * (S_ * HD_);
  const int tid = threadIdx.x, wid = tid >> 6, lane = tid & 63;
  const int l15 = lane & 15, lg = lane >> 4;

  // Q A-frags for both 16-row tiles: row = il (l15), k = d
  bf16x8 qa[2][2];
#pragma unroll
  for (int mt = 0; mt < 2; ++mt) {
    const size_t qaddr = base + (size_t)(i0 + mt * 16 + l15) * HD_ + lg * 8;
    qa[mt][0] = *(const bf16x8*)&Qb[qaddr];
    qa[mt][1] = *(const bf16x8*)&Qb[qaddr + 32];
  }

  // stage bias tile (32x384 bf16) -> lgs f32 (coalesced)
  {
    const unsigned short* bsrc = Bias + ((size_t)bh * S_ + i0) * S_;
#pragma unroll
    for (int it = 0; it < 6; ++it) {
      int e = it * 256 + tid;  // 1536 chunks of 8 elems
      int row = e / 48, c8 = (e % 48) * 8;
      ushort4 v0 = *(const ushort4*)&bsrc[(size_t)row * S_ + c8];
      ushort4 v1 = *(const ushort4*)&bsrc[(size_t)row * S_ + c8 + 4];
      float4 f0 = {bf16_to_f32(v0.x), bf16_to_f32(v0.y),
                   bf16_to_f32(v0.z), bf16_to_f32(v0.w)};
      float4 f1 = {bf16_to_f32(v1.x), bf16_to_f32(v1.y),
                   bf16_to_f32(v1.z), bf16_to_f32(v1.w)};
      *(float4*)&lgs[row][c8] = f0;
      *(float4*)&lgs[row][c8 + 4] = f1;
    }
  }
  __syncthreads();

  // ---- QK^T: wave covers jH = wid*6..+5; K-frags feed both row-tiles
#pragma unroll
  for (int t = 0; t < 6; ++t) {
    const int j0 = (wid * 6 + t) * 16;
    const size_t kaddr = base + (size_t)(j0 + l15) * HD_ + lg * 8;
    bf16x8 kb0 = *(const bf16x8*)&Kb[kaddr];
    bf16x8 kb1 = *(const bf16x8*)&Kb[kaddr + 32];
#pragma unroll
    for (int mt = 0; mt < 2; ++mt) {
      f32x4 d = {0.f, 0.f, 0.f, 0.f};
      d = __builtin_amdgcn_mfma_f32_16x16x32_bf16(qa[mt][0], kb0, d, 0, 0, 0);
      d = __builtin_amdgcn_mfma_f32_16x16x32_bf16(qa[mt][1], kb1, d, 0, 0, 0);
#pragma unroll
      for (int rr = 0; rr < 4; ++rr) {  // D: row = lg*4+rr, col = l15
        const int il = mt * 16 + lg * 4 + rr;
        lgs[il][j0 + l15] = fmaf(d[rr], 0.125f, lgs[il][j0 + l15]);
      }
    }
  }
  __syncthreads();

  // ---- softmax: 2 passes x (16 rows, 16 lanes/row); in-place bf16 pack
  unsigned short* us = (unsigned short*)&lgs[0][0];
#pragma unroll
  for (int p = 0; p < 2; ++p) {
    const int row = p * 16 + (tid >> 4);
    const int l16 = tid & 15;
    float m = -1e30f;
    for (int j = l16; j < S_; j += 16) m = fmaxf(m, lgs[row][j]);
#pragma unroll
    for (int o = 8; o; o >>= 1) m = fmaxf(m, __shfl_xor(m, o, 16));
    float s = 0.f;
    for (int j = l16; j < S_; j += 16) {
      float e = __expf(lgs[row][j] - m);
      lgs[row][j] = e;
      s += e;
    }
#pragma unroll
    for (int o = 8; o; o >>= 1) s += __shfl_xor(s, o, 16);
    const float inv = 1.0f / s;
    float* ao = attn_out + ((size_t)bh * S_ + i0 + row) * S_;
    for (int j = l16; j < S_; j += 16) {
      float pv = lgs[row][j] * inv;
      ao[j] = pv;
      us[row * 816 + j] = f32_to_bf16(pv);  // clobbers f32 col j/2 (consumed)
    }
  }
  __syncthreads();

  // ---- PV: wave wid -> d0 = wid*16; Vt frag reused for both row-tiles
  {
    const int d0 = wid * 16;
    f32x4 acc[2] = {{0.f, 0.f, 0.f, 0.f}, {0.f, 0.f, 0.f, 0.f}};
#pragma unroll
    for (int kc = 0; kc < 12; ++kc) {
      bf16x8 vb =
          *(const bf16x8*)&Vt[base + (size_t)(d0 + l15) * S_ + kc * 32 + lg * 8];
#pragma unroll
      for (int mt = 0; mt < 2; ++mt) {
        bf16x8 pa =
            *(const bf16x8*)&us[(size_t)(mt * 16 + l15) * 816 + kc * 32 + lg * 8];
        acc[mt] = __builtin_amdgcn_mfma_f32_16x16x32_bf16(pa, vb, acc[mt], 0, 0, 0);
      }
    }
    const int b = bh >> 4, hh = bh & 15;
#pragma unroll
    for (int mt = 0; mt < 2; ++mt)
#pragma unroll
      for (int rr = 0; rr < 4; ++rr) {
        const int il = mt * 16 + lg * 4 + rr;
        Vals[((size_t)(b * S_ + i0 + il)) * D_ + hh * HD_ + d0 + l15] =
            f32_to_bf16(acc[mt][rr]);
      }
  }
}

// ---------------------------------------------------------------------------
extern "C" void kernel_launch(void* const* d_in, const int* in_sizes, int n_in,
                              void* d_out, int out_size, void* d_ws,
                              size_t ws_size, hipStream_t stream) {
  (void)in_sizes; (void)n_in; (void)out_size; (void)ws_size;
  const float* x     = (const float*)d_in[0];  // (8,384,1024)
  const float* qkv_w = (const float*)d_in[1];  // (1024,3072)
  const float* qkv_b = (const float*)d_in[2];  // (3072,)
  const float* out_w = (const float*)d_in[3];  // (1024,1024)
  const float* out_b = (const float*)d_in[4];  // (1024,)
  const float* rpe   = (const float*)d_in[5];  // (1023,1024)

  float* out  = (float*)d_out;        // 3145728 f32
  float* attn = out + 3145728;        // 18874368 f32 (probs, written by attn3)

  unsigned short* ws  = (unsigned short*)d_ws;
  unsigned short* xb  = ws;                 // 3072*1024
  unsigned short* Wt  = xb + 3145728;       // 3072*1024 (qkv_w^T)
  unsigned short* Wot = Wt + 3145728;       // 1024*1024 (out_w^T)
  unsigned short* Tb  = Wot + 1048576;      // 1023*1024
  unsigned short* Qb  = Tb + 1047552;       // (b,h,s,hd)
  unsigned short* Kb  = Qb + 3145728;       // (b,h,s,hd)
  unsigned short* Vt  = Kb + 3145728;       // (b,h,hd,s)  transposed V
  unsigned short* Vals = Vt + 3145728;      // (b*s, 1024) bf16
  unsigned short* Bias = Vals + 3145728;    // (b,h,s,s) bf16 staged XL bias

  // 1) fused prep (casts + transposes)
  prep_kernel<<<8191, 256, 0, stream>>>(x, rpe, qkv_w, out_w, xb, Tb, Wt, Wot);

  // 2) QKV projection (M=3072, N=3072); V written transposed
  gemm_bt_kernel<0><<<dim3(24, 24), 256, 0, stream>>>(xb, Wt, qkv_b, Qb, Kb, Vt, nullptr);

  // 3) XL relative bias (MFMA, b-shared) -> bf16 workspace
  bias_kernel<<<dim3(16, 24, 3), 512, 0, stream>>>(Qb, Tb, Bias);

  // 4) fused QK^T(+bias) -> softmax -> PV, 32 rows/block
  attn3_kernel<<<dim3(128, 12), 256, 0, stream>>>(Qb, Kb, Vt, Bias, attn, Vals);

  // 5) output projection (M=3072, N=1024)
  gemm_bt_kernel<1><<<dim3(24, 8), 256, 0, stream>>>(Vals, Wot, out_b, nullptr, nullptr, nullptr, out);
}